// Round 1
// baseline (576.927 us; speedup 1.0000x reference)
//
#include <hip/hip_runtime.h>
#include <hip/hip_bf16.h>

// GCN 2-layer + edge predictor.
// Pipeline per call:
//  1. cnt[i] = #edges with dst==i           (memset + int atomics)
//  2. dinv[i] = rsqrt(cnt[i]+1)             (self-loop included)
//  3. row_ptr = exclusive scan(cnt); cursor = row_ptr   (single-block scan)
//  4. col_idx CSR fill                       (atomic cursor)
//  5. y1 = (X @ W1) * dinv[row]              (LDS-staged GEMM, COLS=128)
//  6. h1[d] = relu(dinv[d]*(y1[d] + sum_{s->d} y1[s]) + b1)  (wave/node)
//  7. y2 = (h1 @ W2) * dinv[row]             (COLS=64)
//  8. h2[d] = dinv[d]*(y2[d] + sum) + b2
//  9. score[e] = dot64(h2[src], h2[dst])     (16 lanes/edge, float4)

#define DIN 128
#define DH  128
#define DOUT 64

__global__ void count_kernel(const int* __restrict__ dst, int* __restrict__ cnt, int E) {
    int e = blockIdx.x * blockDim.x + threadIdx.x;
    if (e < E) atomicAdd(&cnt[dst[e]], 1);
}

__global__ void dinv_kernel(const int* __restrict__ cnt, float* __restrict__ dinv, int n) {
    int i = blockIdx.x * blockDim.x + threadIdx.x;
    if (i < n) dinv[i] = rsqrtf((float)(cnt[i] + 1));
}

// Single-block exclusive scan over n (<= 1024*chunk) elements.
__global__ __launch_bounds__(1024) void scan_kernel(const int* __restrict__ cnt,
                                                    int* __restrict__ row_ptr,
                                                    int* __restrict__ cursor,
                                                    int n, int total) {
    __shared__ int lds[1024];
    int t = threadIdx.x;
    int chunk = (n + 1023) / 1024;
    int beg = t * chunk;
    int end = beg + chunk; if (end > n) end = n;
    int s = 0;
    for (int i = beg; i < end; ++i) s += cnt[i];
    lds[t] = s;
    __syncthreads();
    // Hillis-Steele inclusive scan
    for (int off = 1; off < 1024; off <<= 1) {
        int v = (t >= off) ? lds[t - off] : 0;
        __syncthreads();
        lds[t] += v;
        __syncthreads();
    }
    int run = lds[t] - s;  // exclusive prefix
    for (int i = beg; i < end; ++i) {
        row_ptr[i] = run; cursor[i] = run;
        run += cnt[i];
    }
    if (t == 0) row_ptr[n] = total;
}

__global__ void scatter_kernel(const int* __restrict__ src, const int* __restrict__ dst,
                               int* __restrict__ cursor, int* __restrict__ col, int E) {
    int e = blockIdx.x * blockDim.x + threadIdx.x;
    if (e < E) {
        int p = atomicAdd(&cursor[dst[e]], 1);
        col[p] = src[e];
    }
}

// Y[r][c] = dinv[r] * sum_k X[r][k]*W[k][c].  16 rows/block, 256 threads.
template <int COLS>
__global__ __launch_bounds__(256) void gemm_kernel(const float* __restrict__ X,
                                                   const float* __restrict__ W,
                                                   const float* __restrict__ dinv,
                                                   float* __restrict__ Y, int nrows) {
    constexpr int CPT = COLS / 16;           // cols per thread (8 or 4)
    __shared__ float Ws[128 * COLS];
    __shared__ float Xs[16][129];            // +1 pad: kills same-bank row aliasing
    int tid = threadIdx.x;
    for (int i = tid * 4; i < 128 * COLS; i += 256 * 4) {
        float4 w = *(const float4*)(W + i);
        *(float4*)(Ws + i) = w;
    }
    int row0 = blockIdx.x * 16;
    for (int i = tid * 4; i < 16 * 128; i += 256 * 4) {
        int r = i >> 7, c = i & 127;
        int gr = row0 + r; if (gr >= nrows) gr = nrows - 1;
        float4 x = *(const float4*)(X + (size_t)gr * 128 + c);
        Xs[r][c] = x.x; Xs[r][c + 1] = x.y; Xs[r][c + 2] = x.z; Xs[r][c + 3] = x.w;
    }
    __syncthreads();
    int r = tid >> 4;        // 0..15
    int g = tid & 15;        // 0..15
    float acc[CPT];
#pragma unroll
    for (int c = 0; c < CPT; ++c) acc[c] = 0.f;
    const float* wbase = Ws + g * CPT;
#pragma unroll 4
    for (int k = 0; k < 128; ++k) {
        float xv = Xs[r][k];
        const float* wr = wbase + k * COLS;
#pragma unroll
        for (int c = 0; c < CPT; ++c) acc[c] = fmaf(xv, wr[c], acc[c]);
    }
    int grow = row0 + r;
    if (grow >= nrows) return;
    float dv = dinv[grow];
    size_t o = (size_t)grow * COLS + g * CPT;
#pragma unroll
    for (int c = 0; c < CPT; c += 4) {
        float4 v = make_float4(acc[c] * dv, acc[c + 1] * dv, acc[c + 2] * dv, acc[c + 3] * dv);
        *(float4*)(Y + o + c) = v;
    }
}

// One wave per node: out[d] = act(dinv[d]*(y[d] + sum_{s in CSR[d]} y[s]) + b)
template <int D, bool RELU>
__global__ __launch_bounds__(256) void agg_kernel(const float* __restrict__ y,
                                                  const int* __restrict__ row_ptr,
                                                  const int* __restrict__ col,
                                                  const float* __restrict__ dinv,
                                                  const float* __restrict__ bias,
                                                  float* __restrict__ out, int n) {
    constexpr int V = D / 64;  // floats per lane (2 for D=128, 1 for D=64)
    int w = (blockIdx.x * 256 + threadIdx.x) >> 6;
    int lane = threadIdx.x & 63;
    if (w >= n) return;
    float acc[V];
    if constexpr (V == 2) {
        float2 t = *(const float2*)(y + (size_t)w * D + lane * 2);
        acc[0] = t.x; acc[1] = t.y;
    } else {
        acc[0] = y[(size_t)w * D + lane];
    }
    int beg = row_ptr[w], end = row_ptr[w + 1];
    for (int i = beg; i < end; ++i) {
        int s = col[i];
        if constexpr (V == 2) {
            float2 t = *(const float2*)(y + (size_t)s * D + lane * 2);
            acc[0] += t.x; acc[1] += t.y;
        } else {
            acc[0] += y[(size_t)s * D + lane];
        }
    }
    float dv = dinv[w];
#pragma unroll
    for (int v = 0; v < V; ++v) {
        float r = fmaf(dv, acc[v], bias[lane * V + v]);
        if (RELU) r = fmaxf(r, 0.f);
        out[(size_t)w * D + lane * V + v] = r;
    }
}

// 16 lanes per edge, float4 per lane over D=64.
__global__ __launch_bounds__(256) void score_kernel(const float* __restrict__ h2,
                                                    const int* __restrict__ src,
                                                    const int* __restrict__ dst,
                                                    float* __restrict__ out, int E) {
    int tid = blockIdx.x * 256 + threadIdx.x;
    int e = tid >> 4;
    if (e >= E) return;
    int q = tid & 15;
    int s = src[e], d = dst[e];
    float4 a = *(const float4*)(h2 + (size_t)s * 64 + q * 4);
    float4 b = *(const float4*)(h2 + (size_t)d * 64 + q * 4);
    float v = a.x * b.x + a.y * b.y + a.z * b.z + a.w * b.w;
    v += __shfl_xor(v, 8);
    v += __shfl_xor(v, 4);
    v += __shfl_xor(v, 2);
    v += __shfl_xor(v, 1);
    if (q == 0) out[e] = v;
}

extern "C" void kernel_launch(void* const* d_in, const int* in_sizes, int n_in,
                              void* d_out, int out_size, void* d_ws, size_t ws_size,
                              hipStream_t stream) {
    const float* X   = (const float*)d_in[0];
    const int*   src = (const int*)d_in[1];
    const int*   dst = (const int*)d_in[2];
    const float* W1  = (const float*)d_in[3];
    const float* b1  = (const float*)d_in[4];
    const float* W2  = (const float*)d_in[5];
    const float* b2  = (const float*)d_in[6];
    float* score = (float*)d_out;

    const int N = in_sizes[0] / DIN;   // 50000
    const int E = in_sizes[1];         // 800000

    // workspace carve-up (256B aligned)
    auto align = [](size_t x) { return (x + 255) & ~(size_t)255; };
    char* p = (char*)d_ws;
    int*   cnt     = (int*)p;               p += align((size_t)N * 4);
    int*   row_ptr = (int*)p;               p += align((size_t)(N + 1) * 4);
    int*   cursor  = (int*)p;               p += align((size_t)N * 4);
    float* dinv    = (float*)p;             p += align((size_t)N * 4);
    int*   col     = (int*)p;               p += align((size_t)E * 4);
    float* y1      = (float*)p;             // N*128 floats; later reused for y2+h2
    float* h1      = y1 + (size_t)N * DH;   // N*128 floats
    float* y2      = y1;                    // alias: y1 dead after h1 computed
    float* h2      = y1 + (size_t)N * DOUT; // second half of y1 region

    hipMemsetAsync(cnt, 0, (size_t)N * 4, stream);

    int eb = (E + 255) / 256;
    int nb = (N + 255) / 256;
    count_kernel<<<eb, 256, 0, stream>>>(dst, cnt, E);
    dinv_kernel<<<nb, 256, 0, stream>>>(cnt, dinv, N);
    scan_kernel<<<1, 1024, 0, stream>>>(cnt, row_ptr, cursor, N, E);
    scatter_kernel<<<eb, 256, 0, stream>>>(src, dst, cursor, col, E);

    int gemm_blocks = (N + 15) / 16;
    gemm_kernel<DH><<<gemm_blocks, 256, 0, stream>>>(X, W1, dinv, y1, N);

    int agg_blocks = (N + 3) / 4;
    agg_kernel<DH, true><<<agg_blocks, 256, 0, stream>>>(y1, row_ptr, col, dinv, b1, h1, N);

    gemm_kernel<DOUT><<<gemm_blocks, 256, 0, stream>>>(h1, W2, dinv, y2, N);
    agg_kernel<DOUT, false><<<agg_blocks, 256, 0, stream>>>(y2, row_ptr, col, dinv, b2, h2, N);

    int score_blocks = (E * 16 + 255) / 256;
    score_kernel<<<score_blocks, 256, 0, stream>>>(h2, src, dst, score, E);
}

// Round 2
// 406.457 us; speedup vs baseline: 1.4194x; 1.4194x over previous
//
#include <hip/hip_runtime.h>
#include <hip/hip_bf16.h>

// GCN 2-layer + edge predictor.
// Pipeline per call:
//  1. cnt[i] = #edges with dst==i             (memset + int atomics)
//  2. hierarchical exclusive scan of cnt -> row_ptr, cursor; dinv fused in
//  3. col_idx CSR fill                        (atomic cursor)
//  4. y1 = (X @ W1) * dinv[row]               (LDS-staged GEMM, COLS=128)
//  5. h1[d] = relu(dinv[d]*(y1[d] + sum_{s->d} y1[s]) + b1)  (wave/node)
//  6. y2 = (h1 @ W2) * dinv[row]              (COLS=64)
//  7. h2[d] = dinv[d]*(y2[d] + sum) + b2
//  8. score[e] = dot64(h2[src], h2[dst])      (16 lanes/edge, float4)

#define DIN 128
#define DH  128
#define DOUT 64

__global__ void count_kernel(const int* __restrict__ dst, int* __restrict__ cnt, int E) {
    int e = blockIdx.x * blockDim.x + threadIdx.x;
    if (e < E) atomicAdd(&cnt[dst[e]], 1);
}

// Phase 1: per-block exclusive scan of cnt into row_ptr; block totals to bsum.
// dinv fused (dinv = rsqrt(deg+1), self-loop).
__global__ __launch_bounds__(256) void block_scan_kernel(const int* __restrict__ cnt,
                                                         int* __restrict__ row_ptr,
                                                         int* __restrict__ bsum,
                                                         float* __restrict__ dinv, int n) {
    __shared__ int lds[256];
    int t = threadIdx.x;
    int i = blockIdx.x * 256 + t;
    int v = (i < n) ? cnt[i] : 0;
    if (i < n) dinv[i] = rsqrtf((float)(v + 1));
    lds[t] = v;
    __syncthreads();
    for (int off = 1; off < 256; off <<= 1) {
        int u = (t >= off) ? lds[t - off] : 0;
        __syncthreads();
        lds[t] += u;
        __syncthreads();
    }
    if (i < n) row_ptr[i] = lds[t] - v;  // local exclusive
    if (t == 255) bsum[blockIdx.x] = lds[255];
}

// Phase 2: single-block exclusive scan of block sums (nb <= 256).
__global__ __launch_bounds__(256) void scan_bsum_kernel(const int* __restrict__ bsum,
                                                        int* __restrict__ boff, int nb) {
    __shared__ int lds[256];
    int t = threadIdx.x;
    int v = (t < nb) ? bsum[t] : 0;
    lds[t] = v;
    __syncthreads();
    for (int off = 1; off < 256; off <<= 1) {
        int u = (t >= off) ? lds[t - off] : 0;
        __syncthreads();
        lds[t] += u;
        __syncthreads();
    }
    if (t < nb) boff[t] = lds[t] - v;
}

// Phase 3: add block offsets in place; mirror into cursor; write sentinel.
__global__ __launch_bounds__(256) void finalize_scan_kernel(int* __restrict__ row_ptr,
                                                            int* __restrict__ cursor,
                                                            const int* __restrict__ boff,
                                                            int n, int total) {
    int i = blockIdx.x * 256 + threadIdx.x;
    if (i < n) {
        int r = row_ptr[i] + boff[blockIdx.x];
        row_ptr[i] = r;
        cursor[i] = r;
    }
    if (i == 0) row_ptr[n] = total;
}

__global__ void scatter_kernel(const int* __restrict__ src, const int* __restrict__ dst,
                               int* __restrict__ cursor, int* __restrict__ col, int E) {
    int e = blockIdx.x * blockDim.x + threadIdx.x;
    if (e < E) {
        int p = atomicAdd(&cursor[dst[e]], 1);
        col[p] = src[e];
    }
}

// Y[r][c] = dinv[r] * sum_k X[r][k]*W[k][c].  16 rows/block, 256 threads.
template <int COLS>
__global__ __launch_bounds__(256) void gemm_kernel(const float* __restrict__ X,
                                                   const float* __restrict__ W,
                                                   const float* __restrict__ dinv,
                                                   float* __restrict__ Y, int nrows) {
    constexpr int CPT = COLS / 16;           // cols per thread (8 or 4)
    __shared__ float Ws[128 * COLS];
    __shared__ float Xs[16][129];            // +1 pad: kills same-bank row aliasing
    int tid = threadIdx.x;
    for (int i = tid * 4; i < 128 * COLS; i += 256 * 4) {
        float4 w = *(const float4*)(W + i);
        *(float4*)(Ws + i) = w;
    }
    int row0 = blockIdx.x * 16;
    for (int i = tid * 4; i < 16 * 128; i += 256 * 4) {
        int r = i >> 7, c = i & 127;
        int gr = row0 + r; if (gr >= nrows) gr = nrows - 1;
        float4 x = *(const float4*)(X + (size_t)gr * 128 + c);
        Xs[r][c] = x.x; Xs[r][c + 1] = x.y; Xs[r][c + 2] = x.z; Xs[r][c + 3] = x.w;
    }
    __syncthreads();
    int r = tid >> 4;        // 0..15
    int g = tid & 15;        // 0..15
    float acc[CPT];
#pragma unroll
    for (int c = 0; c < CPT; ++c) acc[c] = 0.f;
    const float* wbase = Ws + g * CPT;
#pragma unroll 4
    for (int k = 0; k < 128; ++k) {
        float xv = Xs[r][k];
        const float* wr = wbase + k * COLS;
#pragma unroll
        for (int c = 0; c < CPT; ++c) acc[c] = fmaf(xv, wr[c], acc[c]);
    }
    int grow = row0 + r;
    if (grow >= nrows) return;
    float dv = dinv[grow];
    size_t o = (size_t)grow * COLS + g * CPT;
#pragma unroll
    for (int c = 0; c < CPT; c += 4) {
        float4 v = make_float4(acc[c] * dv, acc[c + 1] * dv, acc[c + 2] * dv, acc[c + 3] * dv);
        *(float4*)(Y + o + c) = v;
    }
}

// One wave per node: out[d] = act(dinv[d]*(y[d] + sum_{s in CSR[d]} y[s]) + b)
// Edge loop manually unrolled x4 for memory-level parallelism (gathers are
// L2/L3-latency-bound; 4 independent row reads in flight per wave).
template <int D, bool RELU>
__global__ __launch_bounds__(256) void agg_kernel(const float* __restrict__ y,
                                                  const int* __restrict__ row_ptr,
                                                  const int* __restrict__ col,
                                                  const float* __restrict__ dinv,
                                                  const float* __restrict__ bias,
                                                  float* __restrict__ out, int n) {
    constexpr int V = D / 64;  // floats per lane (2 for D=128, 1 for D=64)
    int w = (blockIdx.x * 256 + threadIdx.x) >> 6;
    int lane = threadIdx.x & 63;
    if (w >= n) return;
    float acc[V];
    if constexpr (V == 2) {
        float2 t = *(const float2*)(y + (size_t)w * D + lane * 2);
        acc[0] = t.x; acc[1] = t.y;
    } else {
        acc[0] = y[(size_t)w * D + lane];
    }
    int beg = row_ptr[w], end = row_ptr[w + 1];
    int i = beg;
    for (; i + 4 <= end; i += 4) {
        int s0 = col[i], s1 = col[i + 1], s2 = col[i + 2], s3 = col[i + 3];
        if constexpr (V == 2) {
            float2 t0 = *(const float2*)(y + (size_t)s0 * D + lane * 2);
            float2 t1 = *(const float2*)(y + (size_t)s1 * D + lane * 2);
            float2 t2 = *(const float2*)(y + (size_t)s2 * D + lane * 2);
            float2 t3 = *(const float2*)(y + (size_t)s3 * D + lane * 2);
            acc[0] += t0.x + t1.x + t2.x + t3.x;
            acc[1] += t0.y + t1.y + t2.y + t3.y;
        } else {
            float t0 = y[(size_t)s0 * D + lane];
            float t1 = y[(size_t)s1 * D + lane];
            float t2 = y[(size_t)s2 * D + lane];
            float t3 = y[(size_t)s3 * D + lane];
            acc[0] += t0 + t1 + t2 + t3;
        }
    }
    for (; i < end; ++i) {
        int s = col[i];
        if constexpr (V == 2) {
            float2 t = *(const float2*)(y + (size_t)s * D + lane * 2);
            acc[0] += t.x; acc[1] += t.y;
        } else {
            acc[0] += y[(size_t)s * D + lane];
        }
    }
    float dv = dinv[w];
#pragma unroll
    for (int v = 0; v < V; ++v) {
        float r = fmaf(dv, acc[v], bias[lane * V + v]);
        if (RELU) r = fmaxf(r, 0.f);
        out[(size_t)w * D + lane * V + v] = r;
    }
}

// 16 lanes per edge, float4 per lane over D=64.
__global__ __launch_bounds__(256) void score_kernel(const float* __restrict__ h2,
                                                    const int* __restrict__ src,
                                                    const int* __restrict__ dst,
                                                    float* __restrict__ out, int E) {
    int tid = blockIdx.x * 256 + threadIdx.x;
    int e = tid >> 4;
    if (e >= E) return;
    int q = tid & 15;
    int s = src[e], d = dst[e];
    float4 a = *(const float4*)(h2 + (size_t)s * 64 + q * 4);
    float4 b = *(const float4*)(h2 + (size_t)d * 64 + q * 4);
    float v = a.x * b.x + a.y * b.y + a.z * b.z + a.w * b.w;
    v += __shfl_xor(v, 8);
    v += __shfl_xor(v, 4);
    v += __shfl_xor(v, 2);
    v += __shfl_xor(v, 1);
    if (q == 0) out[e] = v;
}

extern "C" void kernel_launch(void* const* d_in, const int* in_sizes, int n_in,
                              void* d_out, int out_size, void* d_ws, size_t ws_size,
                              hipStream_t stream) {
    const float* X   = (const float*)d_in[0];
    const int*   src = (const int*)d_in[1];
    const int*   dst = (const int*)d_in[2];
    const float* W1  = (const float*)d_in[3];
    const float* b1  = (const float*)d_in[4];
    const float* W2  = (const float*)d_in[5];
    const float* b2  = (const float*)d_in[6];
    float* score = (float*)d_out;

    const int N = in_sizes[0] / DIN;   // 50000
    const int E = in_sizes[1];         // 800000
    const int NB = (N + 255) / 256;    // scan blocks (196)

    // workspace carve-up (256B aligned)
    auto align = [](size_t x) { return (x + 255) & ~(size_t)255; };
    char* p = (char*)d_ws;
    int*   cnt     = (int*)p;               p += align((size_t)N * 4);
    int*   row_ptr = (int*)p;               p += align((size_t)(N + 1) * 4);
    int*   cursor  = (int*)p;               p += align((size_t)N * 4);
    float* dinv    = (float*)p;             p += align((size_t)N * 4);
    int*   bsum    = (int*)p;               p += align(256 * 4);
    int*   boff    = (int*)p;               p += align(256 * 4);
    int*   col     = (int*)p;               p += align((size_t)E * 4);
    float* y1      = (float*)p;             // N*128 floats; later reused for y2+h2
    float* h1      = y1 + (size_t)N * DH;   // N*128 floats
    float* y2      = y1;                    // alias: y1 dead after h1 computed
    float* h2      = y1 + (size_t)N * DOUT; // second half of y1 region

    hipMemsetAsync(cnt, 0, (size_t)N * 4, stream);

    int eb = (E + 255) / 256;
    count_kernel<<<eb, 256, 0, stream>>>(dst, cnt, E);
    block_scan_kernel<<<NB, 256, 0, stream>>>(cnt, row_ptr, bsum, dinv, N);
    scan_bsum_kernel<<<1, 256, 0, stream>>>(bsum, boff, NB);
    finalize_scan_kernel<<<NB, 256, 0, stream>>>(row_ptr, cursor, boff, N, E);
    scatter_kernel<<<eb, 256, 0, stream>>>(src, dst, cursor, col, E);

    int gemm_blocks = (N + 15) / 16;
    gemm_kernel<DH><<<gemm_blocks, 256, 0, stream>>>(X, W1, dinv, y1, N);

    int agg_blocks = (N + 3) / 4;
    agg_kernel<DH, true><<<agg_blocks, 256, 0, stream>>>(y1, row_ptr, col, dinv, b1, h1, N);

    gemm_kernel<DOUT><<<gemm_blocks, 256, 0, stream>>>(h1, W2, dinv, y2, N);
    agg_kernel<DOUT, false><<<agg_blocks, 256, 0, stream>>>(y2, row_ptr, col, dinv, b2, h2, N);

    int score_blocks = (E * 16 + 255) / 256;
    score_kernel<<<score_blocks, 256, 0, stream>>>(h2, src, dst, score, E);
}

// Round 3
// 359.034 us; speedup vs baseline: 1.6069x; 1.1321x over previous
//
#include <hip/hip_runtime.h>
#include <hip/hip_bf16.h>

// GCN 2-layer + edge predictor.
// Pipeline per call:
//  1. cnt[i] = #edges with dst==i             (memset + int atomics)
//  2. hierarchical exclusive scan of cnt -> row_ptr, cursor; dinv fused in
//  3. col_idx CSR fill                        (atomic cursor)
//  4. y1 = (X @ W1) * dinv[row]               (register-tiled GEMM, COLS=128)
//  5. h1[d] = relu(dinv[d]*(y1[d] + sum_{s->d} y1[s]) + b1)  (wave/node)
//  6. y2 = (h1 @ W2) * dinv[row]              (COLS=64)
//  7. h2[d] = dinv[d]*(y2[d] + sum) + b2
//  8. score[e] = dot64(h2[src], h2[dst])      (16 lanes/edge, float4)

#define DIN 128
#define DH  128
#define DOUT 64

__global__ void count_kernel(const int* __restrict__ dst, int* __restrict__ cnt, int E) {
    int e = blockIdx.x * blockDim.x + threadIdx.x;
    if (e < E) atomicAdd(&cnt[dst[e]], 1);
}

// Phase 1: per-block exclusive scan of cnt into row_ptr; block totals to bsum.
// dinv fused (dinv = rsqrt(deg+1), self-loop).
__global__ __launch_bounds__(256) void block_scan_kernel(const int* __restrict__ cnt,
                                                         int* __restrict__ row_ptr,
                                                         int* __restrict__ bsum,
                                                         float* __restrict__ dinv, int n) {
    __shared__ int lds[256];
    int t = threadIdx.x;
    int i = blockIdx.x * 256 + t;
    int v = (i < n) ? cnt[i] : 0;
    if (i < n) dinv[i] = rsqrtf((float)(v + 1));
    lds[t] = v;
    __syncthreads();
    for (int off = 1; off < 256; off <<= 1) {
        int u = (t >= off) ? lds[t - off] : 0;
        __syncthreads();
        lds[t] += u;
        __syncthreads();
    }
    if (i < n) row_ptr[i] = lds[t] - v;  // local exclusive
    if (t == 255) bsum[blockIdx.x] = lds[255];
}

// Phase 2: single-block exclusive scan of block sums (nb <= 256).
__global__ __launch_bounds__(256) void scan_bsum_kernel(const int* __restrict__ bsum,
                                                        int* __restrict__ boff, int nb) {
    __shared__ int lds[256];
    int t = threadIdx.x;
    int v = (t < nb) ? bsum[t] : 0;
    lds[t] = v;
    __syncthreads();
    for (int off = 1; off < 256; off <<= 1) {
        int u = (t >= off) ? lds[t - off] : 0;
        __syncthreads();
        lds[t] += u;
        __syncthreads();
    }
    if (t < nb) boff[t] = lds[t] - v;
}

// Phase 3: add block offsets in place; mirror into cursor; write sentinel.
__global__ __launch_bounds__(256) void finalize_scan_kernel(int* __restrict__ row_ptr,
                                                            int* __restrict__ cursor,
                                                            const int* __restrict__ boff,
                                                            int n, int total) {
    int i = blockIdx.x * 256 + threadIdx.x;
    if (i < n) {
        int r = row_ptr[i] + boff[blockIdx.x];
        row_ptr[i] = r;
        cursor[i] = r;
    }
    if (i == 0) row_ptr[n] = total;
}

__global__ void scatter_kernel(const int* __restrict__ src, const int* __restrict__ dst,
                               int* __restrict__ cursor, int* __restrict__ col, int E) {
    int e = blockIdx.x * blockDim.x + threadIdx.x;
    if (e < E) {
        int p = atomicAdd(&cursor[dst[e]], 1);
        col[p] = src[e];
    }
}

// Register-tiled GEMM: Y[r][c] = dinv[r] * sum_k X[r][k]*W[k][c].
// Block: 128 rows x COLS cols, 256 threads, thread tile 8 x (COLS/16).
// K staged in chunks of 16. Xs stored k-major (transposed, pad 132):
//   - scatter writes during staging: banks (4k + r) % 32 -> 2-way max (free)
//   - reads Xs[k][ty*8 + j]: 4 distinct bank-groups, 16-lane broadcast (free)
// Ws[k][COLS]: reads at tx*4 stride -> 2-way (free). All LDS I/O is b128.
template <int COLS>
__global__ __launch_bounds__(256) void gemm_kernel(const float* __restrict__ X,
                                                   const float* __restrict__ W,
                                                   const float* __restrict__ dinv,
                                                   float* __restrict__ Y, int nrows) {
    constexpr int CPT = COLS / 16;           // cols per thread: 8 (DH) or 4 (DOUT)
    __shared__ float Xs[16][132];            // [k][row], padded
    __shared__ float Ws[16][COLS];           // [k][col]
    int tid = threadIdx.x;
    int tx = tid & 15;                       // column group
    int ty = tid >> 4;                       // row group (8 rows each)
    int row0 = blockIdx.x * 128;

    float acc[8][CPT];
#pragma unroll
    for (int i = 0; i < 8; ++i)
#pragma unroll
        for (int j = 0; j < CPT; ++j) acc[i][j] = 0.f;

    for (int kc = 0; kc < 128; kc += 16) {
        __syncthreads();                     // previous chunk's reads done
        // stage X chunk: 128 rows x 16 k = 512 float4
#pragma unroll
        for (int it = 0; it < 2; ++it) {
            int idx = tid + it * 256;        // [0,512)
            int r = idx >> 2;                // 0..127
            int kk = (idx & 3) * 4;          // 0,4,8,12
            int gr = row0 + r; if (gr >= nrows) gr = nrows - 1;
            float4 v = *(const float4*)(X + (size_t)gr * 128 + kc + kk);
            Xs[kk + 0][r] = v.x; Xs[kk + 1][r] = v.y;
            Xs[kk + 2][r] = v.z; Xs[kk + 3][r] = v.w;
        }
        // stage W chunk: 16 x COLS floats (linear copy)
#pragma unroll
        for (int idx = tid; idx < 16 * COLS / 4; idx += 256) {
            int kr = idx / (COLS / 4);
            int c4 = idx % (COLS / 4);
            *(float4*)&Ws[kr][c4 * 4] =
                *(const float4*)(W + (size_t)(kc + kr) * COLS + c4 * 4);
        }
        __syncthreads();
#pragma unroll
        for (int k = 0; k < 16; ++k) {
            float a[8];
            *(float4*)&a[0] = *(const float4*)&Xs[k][ty * 8];
            *(float4*)&a[4] = *(const float4*)&Xs[k][ty * 8 + 4];
            float b[CPT];
            *(float4*)&b[0] = *(const float4*)&Ws[k][tx * 4];
            if constexpr (CPT == 8)
                *(float4*)&b[4] = *(const float4*)&Ws[k][64 + tx * 4];
#pragma unroll
            for (int i = 0; i < 8; ++i)
#pragma unroll
                for (int j = 0; j < CPT; ++j)
                    acc[i][j] = fmaf(a[i], b[j], acc[i][j]);
        }
    }
    // epilogue: scale by dinv[row], store coalesced float4
#pragma unroll
    for (int i = 0; i < 8; ++i) {
        int gr = row0 + ty * 8 + i;
        if (gr >= nrows) continue;
        float dv = dinv[gr];
        float4 o;
        o.x = acc[i][0] * dv; o.y = acc[i][1] * dv;
        o.z = acc[i][2] * dv; o.w = acc[i][3] * dv;
        *(float4*)(Y + (size_t)gr * COLS + tx * 4) = o;
        if constexpr (CPT == 8) {
            float4 o2;
            o2.x = acc[i][4] * dv; o2.y = acc[i][5] * dv;
            o2.z = acc[i][6] * dv; o2.w = acc[i][7] * dv;
            *(float4*)(Y + (size_t)gr * COLS + 64 + tx * 4) = o2;
        }
    }
}

// One wave per node: out[d] = act(dinv[d]*(y[d] + sum_{s in CSR[d]} y[s]) + b)
// Edge loop manually unrolled x4 for memory-level parallelism (gathers are
// L2/L3-latency-bound; 4 independent row reads in flight per wave).
template <int D, bool RELU>
__global__ __launch_bounds__(256) void agg_kernel(const float* __restrict__ y,
                                                  const int* __restrict__ row_ptr,
                                                  const int* __restrict__ col,
                                                  const float* __restrict__ dinv,
                                                  const float* __restrict__ bias,
                                                  float* __restrict__ out, int n) {
    constexpr int V = D / 64;  // floats per lane (2 for D=128, 1 for D=64)
    int w = (blockIdx.x * 256 + threadIdx.x) >> 6;
    int lane = threadIdx.x & 63;
    if (w >= n) return;
    float acc[V];
    if constexpr (V == 2) {
        float2 t = *(const float2*)(y + (size_t)w * D + lane * 2);
        acc[0] = t.x; acc[1] = t.y;
    } else {
        acc[0] = y[(size_t)w * D + lane];
    }
    int beg = row_ptr[w], end = row_ptr[w + 1];
    int i = beg;
    for (; i + 4 <= end; i += 4) {
        int s0 = col[i], s1 = col[i + 1], s2 = col[i + 2], s3 = col[i + 3];
        if constexpr (V == 2) {
            float2 t0 = *(const float2*)(y + (size_t)s0 * D + lane * 2);
            float2 t1 = *(const float2*)(y + (size_t)s1 * D + lane * 2);
            float2 t2 = *(const float2*)(y + (size_t)s2 * D + lane * 2);
            float2 t3 = *(const float2*)(y + (size_t)s3 * D + lane * 2);
            acc[0] += t0.x + t1.x + t2.x + t3.x;
            acc[1] += t0.y + t1.y + t2.y + t3.y;
        } else {
            float t0 = y[(size_t)s0 * D + lane];
            float t1 = y[(size_t)s1 * D + lane];
            float t2 = y[(size_t)s2 * D + lane];
            float t3 = y[(size_t)s3 * D + lane];
            acc[0] += t0 + t1 + t2 + t3;
        }
    }
    for (; i < end; ++i) {
        int s = col[i];
        if constexpr (V == 2) {
            float2 t = *(const float2*)(y + (size_t)s * D + lane * 2);
            acc[0] += t.x; acc[1] += t.y;
        } else {
            acc[0] += y[(size_t)s * D + lane];
        }
    }
    float dv = dinv[w];
#pragma unroll
    for (int v = 0; v < V; ++v) {
        float r = fmaf(dv, acc[v], bias[lane * V + v]);
        if (RELU) r = fmaxf(r, 0.f);
        out[(size_t)w * D + lane * V + v] = r;
    }
}

// 16 lanes per edge, float4 per lane over D=64.
__global__ __launch_bounds__(256) void score_kernel(const float* __restrict__ h2,
                                                    const int* __restrict__ src,
                                                    const int* __restrict__ dst,
                                                    float* __restrict__ out, int E) {
    int tid = blockIdx.x * 256 + threadIdx.x;
    int e = tid >> 4;
    if (e >= E) return;
    int q = tid & 15;
    int s = src[e], d = dst[e];
    float4 a = *(const float4*)(h2 + (size_t)s * 64 + q * 4);
    float4 b = *(const float4*)(h2 + (size_t)d * 64 + q * 4);
    float v = a.x * b.x + a.y * b.y + a.z * b.z + a.w * b.w;
    v += __shfl_xor(v, 8);
    v += __shfl_xor(v, 4);
    v += __shfl_xor(v, 2);
    v += __shfl_xor(v, 1);
    if (q == 0) out[e] = v;
}

extern "C" void kernel_launch(void* const* d_in, const int* in_sizes, int n_in,
                              void* d_out, int out_size, void* d_ws, size_t ws_size,
                              hipStream_t stream) {
    const float* X   = (const float*)d_in[0];
    const int*   src = (const int*)d_in[1];
    const int*   dst = (const int*)d_in[2];
    const float* W1  = (const float*)d_in[3];
    const float* b1  = (const float*)d_in[4];
    const float* W2  = (const float*)d_in[5];
    const float* b2  = (const float*)d_in[6];
    float* score = (float*)d_out;

    const int N = in_sizes[0] / DIN;   // 50000
    const int E = in_sizes[1];         // 800000
    const int NB = (N + 255) / 256;    // scan blocks (196)

    // workspace carve-up (256B aligned)
    auto align = [](size_t x) { return (x + 255) & ~(size_t)255; };
    char* p = (char*)d_ws;
    int*   cnt     = (int*)p;               p += align((size_t)N * 4);
    int*   row_ptr = (int*)p;               p += align((size_t)(N + 1) * 4);
    int*   cursor  = (int*)p;               p += align((size_t)N * 4);
    float* dinv    = (float*)p;             p += align((size_t)N * 4);
    int*   bsum    = (int*)p;               p += align(256 * 4);
    int*   boff    = (int*)p;               p += align(256 * 4);
    int*   col     = (int*)p;               p += align((size_t)E * 4);
    float* y1      = (float*)p;             // N*128 floats; later reused for y2+h2
    float* h1      = y1 + (size_t)N * DH;   // N*128 floats
    float* y2      = y1;                    // alias: y1 dead after h1 computed
    float* h2      = y1 + (size_t)N * DOUT; // second half of y1 region

    hipMemsetAsync(cnt, 0, (size_t)N * 4, stream);

    int eb = (E + 255) / 256;
    count_kernel<<<eb, 256, 0, stream>>>(dst, cnt, E);
    block_scan_kernel<<<NB, 256, 0, stream>>>(cnt, row_ptr, bsum, dinv, N);
    scan_bsum_kernel<<<1, 256, 0, stream>>>(bsum, boff, NB);
    finalize_scan_kernel<<<NB, 256, 0, stream>>>(row_ptr, cursor, boff, N, E);
    scatter_kernel<<<eb, 256, 0, stream>>>(src, dst, cursor, col, E);

    int gemm_blocks = (N + 127) / 128;
    gemm_kernel<DH><<<gemm_blocks, 256, 0, stream>>>(X, W1, dinv, y1, N);

    int agg_blocks = (N + 3) / 4;
    agg_kernel<DH, true><<<agg_blocks, 256, 0, stream>>>(y1, row_ptr, col, dinv, b1, h1, N);

    gemm_kernel<DOUT><<<gemm_blocks, 256, 0, stream>>>(h1, W2, dinv, y2, N);
    agg_kernel<DOUT, false><<<agg_blocks, 256, 0, stream>>>(y2, row_ptr, col, dinv, b2, h2, N);

    int score_blocks = (E * 16 + 255) / 256;
    score_kernel<<<score_blocks, 256, 0, stream>>>(h2, src, dst, score, E);
}

// Round 4
// 299.729 us; speedup vs baseline: 1.9248x; 1.1979x over previous
//
#include <hip/hip_runtime.h>
#include <hip/hip_bf16.h>

// GCN 2-layer + edge predictor.
// Pipeline per call:
//  1. bucket_count: 196 buckets (dst>>8), per-block LDS hist -> gcnt
//  2. scan_buckets: exclusive scan of gcnt -> gbase/gcursor (1 block, 196 vals)
//  3. bucket_place: per-block LDS hist + one global claim per (block,bucket);
//     writes (src,dst) pairs into bucket regions in ~contiguous runs
//  4. bucket_csr: one block per bucket, LDS counting sort by dst&255 ->
//     coalesced col[], row_ptr[], dinv[]  (replaces atomic-cursor scatter)
//  5. y1 = (X @ W1) * dinv[row]   (register-tiled GEMM, COLS=128)
//  6. h1[d] = relu(dinv[d]*(y1[d] + sum_{s->d} y1[s]) + b1)  (wave/node, x8 MLP)
//  7. y2 = (h1 @ W2) * dinv[row]  (COLS=64)
//  8. h2[d] = dinv[d]*(y2[d] + sum) + b2
//  9. score[e] = dot64(h2[src], h2[dst])  (16 lanes/edge, float4)

#define DIN 128
#define DH  128
#define DOUT 64
#define CAP 8192   // max edges per 256-node bucket (mean ~4096, sigma ~64)

__global__ __launch_bounds__(256) void bucket_count_kernel(const int* __restrict__ dst,
                                                           int* __restrict__ gcnt,
                                                           int E, int nbuck) {
    __shared__ int hist[256];
    int t = threadIdx.x;
    hist[t] = 0;
    __syncthreads();
    int base = blockIdx.x * 4096 + t;
#pragma unroll
    for (int it = 0; it < 16; ++it) {
        int e = base + it * 256;
        if (e < E) atomicAdd(&hist[dst[e] >> 8], 1);
    }
    __syncthreads();
    if (t < nbuck && hist[t]) atomicAdd(&gcnt[t], hist[t]);
}

__global__ __launch_bounds__(256) void scan_buckets_kernel(const int* __restrict__ gcnt,
                                                           int* __restrict__ gbase,
                                                           int* __restrict__ gcursor,
                                                           int* __restrict__ row_ptr,
                                                           int nbuck, int N, int E) {
    __shared__ int lds[256];
    int t = threadIdx.x;
    int v = (t < nbuck) ? gcnt[t] : 0;
    lds[t] = v;
    __syncthreads();
    for (int off = 1; off < 256; off <<= 1) {
        int u = (t >= off) ? lds[t - off] : 0;
        __syncthreads();
        lds[t] += u;
        __syncthreads();
    }
    int ex = lds[t] - v;
    if (t < nbuck) { gbase[t] = ex; gcursor[t] = ex; }
    if (t == 0) { gbase[nbuck] = E; row_ptr[N] = E; }
}

__global__ __launch_bounds__(256) void bucket_place_kernel(const int* __restrict__ src,
                                                           const int* __restrict__ dst,
                                                           int* __restrict__ gcursor,
                                                           uint2* __restrict__ tmp,
                                                           int E, int nbuck) {
    __shared__ int hist[256];
    __shared__ int cur[256];
    int t = threadIdx.x;
    hist[t] = 0;
    __syncthreads();
    int base = blockIdx.x * 4096 + t;
    int d[16];
#pragma unroll
    for (int it = 0; it < 16; ++it) {
        int e = base + it * 256;
        d[it] = (e < E) ? dst[e] : -1;
        if (d[it] >= 0) atomicAdd(&hist[d[it] >> 8], 1);
    }
    __syncthreads();
    if (t < nbuck && hist[t]) cur[t] = atomicAdd(&gcursor[t], hist[t]);
    __syncthreads();
#pragma unroll
    for (int it = 0; it < 16; ++it) {
        int e = base + it * 256;
        if (d[it] >= 0) {
            int r = atomicAdd(&cur[d[it] >> 8], 1);
            tmp[r] = make_uint2((unsigned)src[e], (unsigned)d[it]);
        }
    }
}

// One block per bucket: LDS counting sort by dst&255 -> col (coalesced),
// row_ptr, dinv.
__global__ __launch_bounds__(256) void bucket_csr_kernel(const uint2* __restrict__ tmp,
                                                         const int* __restrict__ gbase,
                                                         int* __restrict__ row_ptr,
                                                         float* __restrict__ dinv,
                                                         int* __restrict__ col, int N) {
    __shared__ int hist[256], cur[256], pfx[256];
    __shared__ unsigned esrc[CAP];
    __shared__ unsigned char eloc[CAP];
    __shared__ unsigned sorted[CAP];
    int b = blockIdx.x, t = threadIdx.x;
    int beg = gbase[b], end = gbase[b + 1];
    int size = end - beg;
    if (size > CAP) size = CAP;  // statistically unreachable; memory-safety
    hist[t] = 0;
    __syncthreads();
    for (int i = t; i < size; i += 256) {
        uint2 e = tmp[beg + i];
        esrc[i] = e.x;
        int loc = e.y & 255;
        eloc[i] = (unsigned char)loc;
        atomicAdd(&hist[loc], 1);
    }
    __syncthreads();
    int v = hist[t];
    pfx[t] = v;
    __syncthreads();
    for (int off = 1; off < 256; off <<= 1) {
        int u = (t >= off) ? pfx[t - off] : 0;
        __syncthreads();
        pfx[t] += u;
        __syncthreads();
    }
    int ex = pfx[t] - v;
    cur[t] = ex;
    int node = b * 256 + t;
    if (node < N) {
        row_ptr[node] = beg + ex;
        dinv[node] = rsqrtf((float)(v + 1));
    }
    __syncthreads();
    for (int i = t; i < size; i += 256) {
        int r = atomicAdd(&cur[eloc[i]], 1);
        sorted[r] = esrc[i];
    }
    __syncthreads();
    for (int i = t; i < size; i += 256) col[beg + i] = (int)sorted[i];
}

// Register-tiled GEMM: Y[r][c] = dinv[r] * sum_k X[r][k]*W[k][c].
// Block: 128 rows x COLS cols, 256 threads, thread tile 8 x (COLS/16).
template <int COLS>
__global__ __launch_bounds__(256) void gemm_kernel(const float* __restrict__ X,
                                                   const float* __restrict__ W,
                                                   const float* __restrict__ dinv,
                                                   float* __restrict__ Y, int nrows) {
    constexpr int CPT = COLS / 16;           // cols per thread: 8 (DH) or 4 (DOUT)
    __shared__ float Xs[16][132];            // [k][row], padded
    __shared__ float Ws[16][COLS];           // [k][col]
    int tid = threadIdx.x;
    int tx = tid & 15;                       // column group
    int ty = tid >> 4;                       // row group (8 rows each)
    int row0 = blockIdx.x * 128;

    float acc[8][CPT];
#pragma unroll
    for (int i = 0; i < 8; ++i)
#pragma unroll
        for (int j = 0; j < CPT; ++j) acc[i][j] = 0.f;

    for (int kc = 0; kc < 128; kc += 16) {
        __syncthreads();
#pragma unroll
        for (int it = 0; it < 2; ++it) {
            int idx = tid + it * 256;        // [0,512)
            int r = idx >> 2;                // 0..127
            int kk = (idx & 3) * 4;          // 0,4,8,12
            int gr = row0 + r; if (gr >= nrows) gr = nrows - 1;
            float4 v = *(const float4*)(X + (size_t)gr * 128 + kc + kk);
            Xs[kk + 0][r] = v.x; Xs[kk + 1][r] = v.y;
            Xs[kk + 2][r] = v.z; Xs[kk + 3][r] = v.w;
        }
#pragma unroll
        for (int idx = tid; idx < 16 * COLS / 4; idx += 256) {
            int kr = idx / (COLS / 4);
            int c4 = idx % (COLS / 4);
            *(float4*)&Ws[kr][c4 * 4] =
                *(const float4*)(W + (size_t)(kc + kr) * COLS + c4 * 4);
        }
        __syncthreads();
#pragma unroll
        for (int k = 0; k < 16; ++k) {
            float a[8];
            *(float4*)&a[0] = *(const float4*)&Xs[k][ty * 8];
            *(float4*)&a[4] = *(const float4*)&Xs[k][ty * 8 + 4];
            float b[CPT];
            *(float4*)&b[0] = *(const float4*)&Ws[k][tx * 4];
            if constexpr (CPT == 8)
                *(float4*)&b[4] = *(const float4*)&Ws[k][64 + tx * 4];
#pragma unroll
            for (int i = 0; i < 8; ++i)
#pragma unroll
                for (int j = 0; j < CPT; ++j)
                    acc[i][j] = fmaf(a[i], b[j], acc[i][j]);
        }
    }
#pragma unroll
    for (int i = 0; i < 8; ++i) {
        int gr = row0 + ty * 8 + i;
        if (gr >= nrows) continue;
        float dv = dinv[gr];
        float4 o;
        o.x = acc[i][0] * dv; o.y = acc[i][1] * dv;
        o.z = acc[i][2] * dv; o.w = acc[i][3] * dv;
        *(float4*)(Y + (size_t)gr * COLS + tx * 4) = o;
        if constexpr (CPT == 8) {
            float4 o2;
            o2.x = acc[i][4] * dv; o2.y = acc[i][5] * dv;
            o2.z = acc[i][6] * dv; o2.w = acc[i][7] * dv;
            *(float4*)(Y + (size_t)gr * COLS + 64 + tx * 4) = o2;
        }
    }
}

// One wave per node: out[d] = act(dinv[d]*(y[d] + sum_{s in CSR[d]} y[s]) + b)
// Edge loop unrolled x8 for memory-level parallelism (gathers are
// latency/fabric-bound; 8 independent 512B row reads in flight per wave).
template <int D, bool RELU>
__global__ __launch_bounds__(256) void agg_kernel(const float* __restrict__ y,
                                                  const int* __restrict__ row_ptr,
                                                  const int* __restrict__ col,
                                                  const float* __restrict__ dinv,
                                                  const float* __restrict__ bias,
                                                  float* __restrict__ out, int n) {
    constexpr int V = D / 64;  // floats per lane (2 for D=128, 1 for D=64)
    int w = (blockIdx.x * 256 + threadIdx.x) >> 6;
    int lane = threadIdx.x & 63;
    if (w >= n) return;
    float acc[V];
    if constexpr (V == 2) {
        float2 t = *(const float2*)(y + (size_t)w * D + lane * 2);
        acc[0] = t.x; acc[1] = t.y;
    } else {
        acc[0] = y[(size_t)w * D + lane];
    }
    int beg = row_ptr[w], end = row_ptr[w + 1];
    int i = beg;
    for (; i + 8 <= end; i += 8) {
        int s[8];
#pragma unroll
        for (int u = 0; u < 8; ++u) s[u] = col[i + u];
        if constexpr (V == 2) {
            float2 tv[8];
#pragma unroll
            for (int u = 0; u < 8; ++u)
                tv[u] = *(const float2*)(y + (size_t)s[u] * D + lane * 2);
#pragma unroll
            for (int u = 0; u < 8; ++u) { acc[0] += tv[u].x; acc[1] += tv[u].y; }
        } else {
            float tv[8];
#pragma unroll
            for (int u = 0; u < 8; ++u) tv[u] = y[(size_t)s[u] * D + lane];
#pragma unroll
            for (int u = 0; u < 8; ++u) acc[0] += tv[u];
        }
    }
    for (; i < end; ++i) {
        int s = col[i];
        if constexpr (V == 2) {
            float2 t = *(const float2*)(y + (size_t)s * D + lane * 2);
            acc[0] += t.x; acc[1] += t.y;
        } else {
            acc[0] += y[(size_t)s * D + lane];
        }
    }
    float dv = dinv[w];
#pragma unroll
    for (int v = 0; v < V; ++v) {
        float r = fmaf(dv, acc[v], bias[lane * V + v]);
        if (RELU) r = fmaxf(r, 0.f);
        out[(size_t)w * D + lane * V + v] = r;
    }
}

// 16 lanes per edge, float4 per lane over D=64.
__global__ __launch_bounds__(256) void score_kernel(const float* __restrict__ h2,
                                                    const int* __restrict__ src,
                                                    const int* __restrict__ dst,
                                                    float* __restrict__ out, int E) {
    int tid = blockIdx.x * 256 + threadIdx.x;
    int e = tid >> 4;
    if (e >= E) return;
    int q = tid & 15;
    int s = src[e], d = dst[e];
    float4 a = *(const float4*)(h2 + (size_t)s * 64 + q * 4);
    float4 b = *(const float4*)(h2 + (size_t)d * 64 + q * 4);
    float v = a.x * b.x + a.y * b.y + a.z * b.z + a.w * b.w;
    v += __shfl_xor(v, 8);
    v += __shfl_xor(v, 4);
    v += __shfl_xor(v, 2);
    v += __shfl_xor(v, 1);
    if (q == 0) out[e] = v;
}

extern "C" void kernel_launch(void* const* d_in, const int* in_sizes, int n_in,
                              void* d_out, int out_size, void* d_ws, size_t ws_size,
                              hipStream_t stream) {
    const float* X   = (const float*)d_in[0];
    const int*   src = (const int*)d_in[1];
    const int*   dst = (const int*)d_in[2];
    const float* W1  = (const float*)d_in[3];
    const float* b1  = (const float*)d_in[4];
    const float* W2  = (const float*)d_in[5];
    const float* b2  = (const float*)d_in[6];
    float* score = (float*)d_out;

    const int N = in_sizes[0] / DIN;     // 50000
    const int E = in_sizes[1];           // 800000
    const int nbuck = (N + 255) / 256;   // 196 buckets
    const int EB = (E + 4095) / 4096;    // edge blocks for bucket passes

    // workspace carve-up (256B aligned)
    auto align = [](size_t x) { return (x + 255) & ~(size_t)255; };
    char* p = (char*)d_ws;
    int*   gcnt    = (int*)p;               p += align(256 * 4);
    int*   gbase   = (int*)p;               p += align(257 * 4);
    int*   gcursor = (int*)p;               p += align(256 * 4);
    int*   row_ptr = (int*)p;               p += align((size_t)(N + 1) * 4);
    float* dinv    = (float*)p;             p += align((size_t)N * 4);
    int*   col     = (int*)p;               p += align((size_t)E * 4);
    uint2* tmp     = (uint2*)p;             p += align((size_t)E * 8);
    float* y1      = (float*)p;             // N*128 floats; later reused for y2+h2
    float* h1      = y1 + (size_t)N * DH;   // N*128 floats
    float* y2      = y1;                    // alias: y1 dead after h1 computed
    float* h2      = y1 + (size_t)N * DOUT; // second half of y1 region

    hipMemsetAsync(gcnt, 0, 256 * 4, stream);

    bucket_count_kernel<<<EB, 256, 0, stream>>>(dst, gcnt, E, nbuck);
    scan_buckets_kernel<<<1, 256, 0, stream>>>(gcnt, gbase, gcursor, row_ptr, nbuck, N, E);
    bucket_place_kernel<<<EB, 256, 0, stream>>>(src, dst, gcursor, tmp, E, nbuck);
    bucket_csr_kernel<<<nbuck, 256, 0, stream>>>(tmp, gbase, row_ptr, dinv, col, N);

    int gemm_blocks = (N + 127) / 128;
    gemm_kernel<DH><<<gemm_blocks, 256, 0, stream>>>(X, W1, dinv, y1, N);

    int agg_blocks = (N + 3) / 4;
    agg_kernel<DH, true><<<agg_blocks, 256, 0, stream>>>(y1, row_ptr, col, dinv, b1, h1, N);

    gemm_kernel<DOUT><<<gemm_blocks, 256, 0, stream>>>(h1, W2, dinv, y2, N);
    agg_kernel<DOUT, false><<<agg_blocks, 256, 0, stream>>>(y2, row_ptr, col, dinv, b2, h2, N);

    int score_blocks = (E * 16 + 255) / 256;
    score_kernel<<<score_blocks, 256, 0, stream>>>(h2, src, dst, score, E);
}

// Round 5
// 269.403 us; speedup vs baseline: 2.1415x; 1.1126x over previous
//
#include <hip/hip_runtime.h>
#include <hip/hip_bf16.h>
#include <type_traits>

// GCN 2-layer + edge predictor. Intermediate tables (y1,h1,y2,h2) stored bf16
// to halve the gather traffic (agg/score are fabric-BW bound at ~3.6 TB/s on
// random row reads); all accumulation in fp32.
//
// Pipeline per call:
//  1. bucket_count / scan_buckets / bucket_place / bucket_csr: counting-sort
//     CSR build (196 buckets of 256 dst)
//  2. y1 = (X @ W1) * dinv[row]            (register-tiled GEMM, fp32 in, bf16 out)
//  3. h1[d] = relu(dinv[d]*(y1[d]+sum)+b1) (wave/node gather, bf16 in/out)
//  4. y2 = (h1 @ W2) * dinv[row]           (bf16 in, bf16 out)
//  5. h2[d] = dinv[d]*(y2[d]+sum)+b2       (bf16)
//  6. score[e] = dot64(h2[src], h2[dst])   (fp32 out)

#define DIN 128
#define DH  128
#define DOUT 64
#define CAP 8192   // max edges per 256-node bucket (mean ~4096)

__device__ inline float2 bf2_to_f2(unsigned u) {
    union { unsigned i; float f; } a, b;
    a.i = u << 16;          // low bf16
    b.i = u & 0xffff0000u;  // high bf16
    return make_float2(a.f, b.f);
}
__device__ inline float bf_to_f(unsigned short u) {
    union { unsigned i; float f; } a;
    a.i = ((unsigned)u) << 16;
    return a.f;
}
__device__ inline unsigned short f_to_bf(float f) {  // RNE
    union { float f; unsigned i; } v; v.f = f;
    unsigned r = v.i + 0x7fffu + ((v.i >> 16) & 1u);
    return (unsigned short)(r >> 16);
}

__global__ __launch_bounds__(256) void bucket_count_kernel(const int* __restrict__ dst,
                                                           int* __restrict__ gcnt,
                                                           int E, int nbuck) {
    __shared__ int hist[256];
    int t = threadIdx.x;
    hist[t] = 0;
    __syncthreads();
    int base = blockIdx.x * 4096 + t;
#pragma unroll
    for (int it = 0; it < 16; ++it) {
        int e = base + it * 256;
        if (e < E) atomicAdd(&hist[dst[e] >> 8], 1);
    }
    __syncthreads();
    if (t < nbuck && hist[t]) atomicAdd(&gcnt[t], hist[t]);
}

__global__ __launch_bounds__(256) void scan_buckets_kernel(const int* __restrict__ gcnt,
                                                           int* __restrict__ gbase,
                                                           int* __restrict__ gcursor,
                                                           int* __restrict__ row_ptr,
                                                           int nbuck, int N, int E) {
    __shared__ int lds[256];
    int t = threadIdx.x;
    int v = (t < nbuck) ? gcnt[t] : 0;
    lds[t] = v;
    __syncthreads();
    for (int off = 1; off < 256; off <<= 1) {
        int u = (t >= off) ? lds[t - off] : 0;
        __syncthreads();
        lds[t] += u;
        __syncthreads();
    }
    int ex = lds[t] - v;
    if (t < nbuck) { gbase[t] = ex; gcursor[t] = ex; }
    if (t == 0) { gbase[nbuck] = E; row_ptr[N] = E; }
}

__global__ __launch_bounds__(256) void bucket_place_kernel(const int* __restrict__ src,
                                                           const int* __restrict__ dst,
                                                           int* __restrict__ gcursor,
                                                           uint2* __restrict__ tmp,
                                                           int E, int nbuck) {
    __shared__ int hist[256];
    __shared__ int cur[256];
    int t = threadIdx.x;
    hist[t] = 0;
    __syncthreads();
    int base = blockIdx.x * 4096 + t;
    int d[16];
#pragma unroll
    for (int it = 0; it < 16; ++it) {
        int e = base + it * 256;
        d[it] = (e < E) ? dst[e] : -1;
        if (d[it] >= 0) atomicAdd(&hist[d[it] >> 8], 1);
    }
    __syncthreads();
    if (t < nbuck && hist[t]) cur[t] = atomicAdd(&gcursor[t], hist[t]);
    __syncthreads();
#pragma unroll
    for (int it = 0; it < 16; ++it) {
        int e = base + it * 256;
        if (d[it] >= 0) {
            int r = atomicAdd(&cur[d[it] >> 8], 1);
            tmp[r] = make_uint2((unsigned)src[e], (unsigned)d[it]);
        }
    }
}

// One block per bucket: LDS counting sort by dst&255 -> col (coalesced),
// row_ptr, dinv.
__global__ __launch_bounds__(256) void bucket_csr_kernel(const uint2* __restrict__ tmp,
                                                         const int* __restrict__ gbase,
                                                         int* __restrict__ row_ptr,
                                                         float* __restrict__ dinv,
                                                         int* __restrict__ col, int N) {
    __shared__ int hist[256], cur[256], pfx[256];
    __shared__ unsigned esrc[CAP];
    __shared__ unsigned char eloc[CAP];
    __shared__ unsigned sorted[CAP];
    int b = blockIdx.x, t = threadIdx.x;
    int beg = gbase[b], end = gbase[b + 1];
    int size = end - beg;
    if (size > CAP) size = CAP;  // statistically unreachable; memory-safety
    hist[t] = 0;
    __syncthreads();
    for (int i = t; i < size; i += 256) {
        uint2 e = tmp[beg + i];
        esrc[i] = e.x;
        int loc = e.y & 255;
        eloc[i] = (unsigned char)loc;
        atomicAdd(&hist[loc], 1);
    }
    __syncthreads();
    int v = hist[t];
    pfx[t] = v;
    __syncthreads();
    for (int off = 1; off < 256; off <<= 1) {
        int u = (t >= off) ? pfx[t - off] : 0;
        __syncthreads();
        pfx[t] += u;
        __syncthreads();
    }
    int ex = pfx[t] - v;
    cur[t] = ex;
    int node = b * 256 + t;
    if (node < N) {
        row_ptr[node] = beg + ex;
        dinv[node] = rsqrtf((float)(v + 1));
    }
    __syncthreads();
    for (int i = t; i < size; i += 256) {
        int r = atomicAdd(&cur[eloc[i]], 1);
        sorted[r] = esrc[i];
    }
    __syncthreads();
    for (int i = t; i < size; i += 256) col[beg + i] = (int)sorted[i];
}

// Register-tiled GEMM: Y[r][c] = dinv[r] * sum_k X[r][k]*W[k][c].
// Block: 128 rows x COLS cols, 256 threads, thread tile 8 x (COLS/16).
// XT = float (layer 1) or ushort bf16 (layer 2). Output bf16.
template <int COLS, typename XT>
__global__ __launch_bounds__(256) void gemm_kernel(const XT* __restrict__ X,
                                                   const float* __restrict__ W,
                                                   const float* __restrict__ dinv,
                                                   unsigned short* __restrict__ Y,
                                                   int nrows) {
    constexpr int CPT = COLS / 16;           // cols per thread: 8 (DH) or 4 (DOUT)
    __shared__ float Xs[16][132];            // [k][row], padded
    __shared__ float Ws[16][COLS];           // [k][col]
    int tid = threadIdx.x;
    int tx = tid & 15;                       // column group
    int ty = tid >> 4;                       // row group (8 rows each)
    int row0 = blockIdx.x * 128;

    float acc[8][CPT];
#pragma unroll
    for (int i = 0; i < 8; ++i)
#pragma unroll
        for (int j = 0; j < CPT; ++j) acc[i][j] = 0.f;

    for (int kc = 0; kc < 128; kc += 16) {
        __syncthreads();
        if constexpr (std::is_same_v<XT, float>) {
            // 128 rows x 16 k = 512 float4
#pragma unroll
            for (int it = 0; it < 2; ++it) {
                int idx = tid + it * 256;    // [0,512)
                int r = idx >> 2;            // 0..127
                int kk = (idx & 3) * 4;      // 0,4,8,12
                int gr = row0 + r; if (gr >= nrows) gr = nrows - 1;
                float4 v = *(const float4*)(X + (size_t)gr * 128 + kc + kk);
                Xs[kk + 0][r] = v.x; Xs[kk + 1][r] = v.y;
                Xs[kk + 2][r] = v.z; Xs[kk + 3][r] = v.w;
            }
        } else {
            // bf16: 128 rows x 16 k = 256 x 16B loads (8 bf16 each)
            int r = tid >> 1;
            int kk = (tid & 1) * 8;
            int gr = row0 + r; if (gr >= nrows) gr = nrows - 1;
            uint4 u = *(const uint4*)(X + (size_t)gr * 128 + kc + kk);
            float2 p;
            p = bf2_to_f2(u.x); Xs[kk + 0][r] = p.x; Xs[kk + 1][r] = p.y;
            p = bf2_to_f2(u.y); Xs[kk + 2][r] = p.x; Xs[kk + 3][r] = p.y;
            p = bf2_to_f2(u.z); Xs[kk + 4][r] = p.x; Xs[kk + 5][r] = p.y;
            p = bf2_to_f2(u.w); Xs[kk + 6][r] = p.x; Xs[kk + 7][r] = p.y;
        }
#pragma unroll
        for (int idx = tid; idx < 16 * COLS / 4; idx += 256) {
            int kr = idx / (COLS / 4);
            int c4 = idx % (COLS / 4);
            *(float4*)&Ws[kr][c4 * 4] =
                *(const float4*)(W + (size_t)(kc + kr) * COLS + c4 * 4);
        }
        __syncthreads();
#pragma unroll
        for (int k = 0; k < 16; ++k) {
            float a[8];
            *(float4*)&a[0] = *(const float4*)&Xs[k][ty * 8];
            *(float4*)&a[4] = *(const float4*)&Xs[k][ty * 8 + 4];
            float b[CPT];
            *(float4*)&b[0] = *(const float4*)&Ws[k][tx * 4];
            if constexpr (CPT == 8)
                *(float4*)&b[4] = *(const float4*)&Ws[k][64 + tx * 4];
#pragma unroll
            for (int i = 0; i < 8; ++i)
#pragma unroll
                for (int j = 0; j < CPT; ++j)
                    acc[i][j] = fmaf(a[i], b[j], acc[i][j]);
        }
    }
    // epilogue: scale by dinv[row], convert bf16, store 8B/16B packed
#pragma unroll
    for (int i = 0; i < 8; ++i) {
        int gr = row0 + ty * 8 + i;
        if (gr >= nrows) continue;
        float dv = dinv[gr];
        ushort4 o;
        o.x = f_to_bf(acc[i][0] * dv); o.y = f_to_bf(acc[i][1] * dv);
        o.z = f_to_bf(acc[i][2] * dv); o.w = f_to_bf(acc[i][3] * dv);
        *(ushort4*)(Y + (size_t)gr * COLS + tx * 4) = o;
        if constexpr (CPT == 8) {
            ushort4 o2;
            o2.x = f_to_bf(acc[i][4] * dv); o2.y = f_to_bf(acc[i][5] * dv);
            o2.z = f_to_bf(acc[i][6] * dv); o2.w = f_to_bf(acc[i][7] * dv);
            *(ushort4*)(Y + (size_t)gr * COLS + 64 + tx * 4) = o2;
        }
    }
}

// One wave per node: out[d] = act(dinv[d]*(y[d] + sum_{s in CSR[d]} y[s]) + b)
// y and out are bf16 tables; accumulate fp32. Edge loop unrolled x8 for MLP.
template <int D, bool RELU>
__global__ __launch_bounds__(256) void agg_kernel(const unsigned short* __restrict__ y,
                                                  const int* __restrict__ row_ptr,
                                                  const int* __restrict__ col,
                                                  const float* __restrict__ dinv,
                                                  const float* __restrict__ bias,
                                                  unsigned short* __restrict__ out, int n) {
    constexpr int V = D / 64;  // bf16 per lane (2 for D=128, 1 for D=64)
    int w = (blockIdx.x * 256 + threadIdx.x) >> 6;
    int lane = threadIdx.x & 63;
    if (w >= n) return;
    float acc[V];
    if constexpr (V == 2) {
        float2 t = bf2_to_f2(*(const unsigned*)(y + (size_t)w * D + lane * 2));
        acc[0] = t.x; acc[1] = t.y;
    } else {
        acc[0] = bf_to_f(y[(size_t)w * D + lane]);
    }
    int beg = row_ptr[w], end = row_ptr[w + 1];
    int i = beg;
    for (; i + 8 <= end; i += 8) {
        int s[8];
#pragma unroll
        for (int u = 0; u < 8; ++u) s[u] = col[i + u];
        if constexpr (V == 2) {
            unsigned tv[8];
#pragma unroll
            for (int u = 0; u < 8; ++u)
                tv[u] = *(const unsigned*)(y + (size_t)s[u] * D + lane * 2);
#pragma unroll
            for (int u = 0; u < 8; ++u) {
                float2 f = bf2_to_f2(tv[u]);
                acc[0] += f.x; acc[1] += f.y;
            }
        } else {
            unsigned short tv[8];
#pragma unroll
            for (int u = 0; u < 8; ++u) tv[u] = y[(size_t)s[u] * D + lane];
#pragma unroll
            for (int u = 0; u < 8; ++u) acc[0] += bf_to_f(tv[u]);
        }
    }
    for (; i < end; ++i) {
        int s = col[i];
        if constexpr (V == 2) {
            float2 f = bf2_to_f2(*(const unsigned*)(y + (size_t)s * D + lane * 2));
            acc[0] += f.x; acc[1] += f.y;
        } else {
            acc[0] += bf_to_f(y[(size_t)s * D + lane]);
        }
    }
    float dv = dinv[w];
    if constexpr (V == 2) {
        float r0 = fmaf(dv, acc[0], bias[lane * 2]);
        float r1 = fmaf(dv, acc[1], bias[lane * 2 + 1]);
        if (RELU) { r0 = fmaxf(r0, 0.f); r1 = fmaxf(r1, 0.f); }
        unsigned pk = (unsigned)f_to_bf(r0) | ((unsigned)f_to_bf(r1) << 16);
        *(unsigned*)(out + (size_t)w * D + lane * 2) = pk;
    } else {
        float r = fmaf(dv, acc[0], bias[lane]);
        if (RELU) r = fmaxf(r, 0.f);
        out[(size_t)w * D + lane] = f_to_bf(r);
    }
}

// 16 lanes per edge, 4 bf16 (8B) per lane over D=64.
__global__ __launch_bounds__(256) void score_kernel(const unsigned short* __restrict__ h2,
                                                    const int* __restrict__ src,
                                                    const int* __restrict__ dst,
                                                    float* __restrict__ out, int E) {
    int tid = blockIdx.x * 256 + threadIdx.x;
    int e = tid >> 4;
    if (e >= E) return;
    int q = tid & 15;
    int s = src[e], d = dst[e];
    uint2 ua = *(const uint2*)(h2 + (size_t)s * 64 + q * 4);
    uint2 ub = *(const uint2*)(h2 + (size_t)d * 64 + q * 4);
    float2 a0 = bf2_to_f2(ua.x), a1 = bf2_to_f2(ua.y);
    float2 b0 = bf2_to_f2(ub.x), b1 = bf2_to_f2(ub.y);
    float v = a0.x * b0.x + a0.y * b0.y + a1.x * b1.x + a1.y * b1.y;
    v += __shfl_xor(v, 8);
    v += __shfl_xor(v, 4);
    v += __shfl_xor(v, 2);
    v += __shfl_xor(v, 1);
    if (q == 0) out[e] = v;
}

extern "C" void kernel_launch(void* const* d_in, const int* in_sizes, int n_in,
                              void* d_out, int out_size, void* d_ws, size_t ws_size,
                              hipStream_t stream) {
    const float* X   = (const float*)d_in[0];
    const int*   src = (const int*)d_in[1];
    const int*   dst = (const int*)d_in[2];
    const float* W1  = (const float*)d_in[3];
    const float* b1  = (const float*)d_in[4];
    const float* W2  = (const float*)d_in[5];
    const float* b2  = (const float*)d_in[6];
    float* score = (float*)d_out;

    const int N = in_sizes[0] / DIN;     // 50000
    const int E = in_sizes[1];           // 800000
    const int nbuck = (N + 255) / 256;   // 196 buckets
    const int EB = (E + 4095) / 4096;    // edge blocks for bucket passes

    // workspace carve-up (256B aligned)
    auto align = [](size_t x) { return (x + 255) & ~(size_t)255; };
    char* p = (char*)d_ws;
    int*   gcnt    = (int*)p;               p += align(256 * 4);
    int*   gbase   = (int*)p;               p += align(257 * 4);
    int*   gcursor = (int*)p;               p += align(256 * 4);
    int*   row_ptr = (int*)p;               p += align((size_t)(N + 1) * 4);
    float* dinv    = (float*)p;             p += align((size_t)N * 4);
    int*   col     = (int*)p;               p += align((size_t)E * 4);
    uint2* tmp     = (uint2*)p;             p += align((size_t)E * 8);
    unsigned short* y1 = (unsigned short*)p; p += align((size_t)N * DH * 2);
    unsigned short* h1 = (unsigned short*)p; p += align((size_t)N * DH * 2);
    unsigned short* y2 = y1;                       // y1 dead after h1
    unsigned short* h2 = y1 + (size_t)N * DOUT;    // second half of y1 region

    hipMemsetAsync(gcnt, 0, 256 * 4, stream);

    bucket_count_kernel<<<EB, 256, 0, stream>>>(dst, gcnt, E, nbuck);
    scan_buckets_kernel<<<1, 256, 0, stream>>>(gcnt, gbase, gcursor, row_ptr, nbuck, N, E);
    bucket_place_kernel<<<EB, 256, 0, stream>>>(src, dst, gcursor, tmp, E, nbuck);
    bucket_csr_kernel<<<nbuck, 256, 0, stream>>>(tmp, gbase, row_ptr, dinv, col, N);

    int gemm_blocks = (N + 127) / 128;
    gemm_kernel<DH, float><<<gemm_blocks, 256, 0, stream>>>(X, W1, dinv, y1, N);

    int agg_blocks = (N + 3) / 4;
    agg_kernel<DH, true><<<agg_blocks, 256, 0, stream>>>(y1, row_ptr, col, dinv, b1, h1, N);

    gemm_kernel<DOUT, unsigned short><<<gemm_blocks, 256, 0, stream>>>(h1, W2, dinv, y2, N);
    agg_kernel<DOUT, false><<<agg_blocks, 256, 0, stream>>>(y2, row_ptr, col, dinv, b2, h2, N);

    int score_blocks = (E * 16 + 255) / 256;
    score_kernel<<<score_blocks, 256, 0, stream>>>(h2, src, dst, score, E);
}

// Round 7
// 261.147 us; speedup vs baseline: 2.2092x; 1.0316x over previous
//
#include <hip/hip_runtime.h>
#include <hip/hip_bf16.h>
#include <type_traits>

// GCN 2-layer + edge predictor. Intermediate tables (y1,h1,y2,h2) stored bf16
// (gathers are fabric-BW bound); GEMMs on MFMA bf16 (inputs rounded to bf16,
// fp32 accumulate). CSR built by bucketed counting sort.
//
// Pipeline per call:
//  1. bucket_count / scan_buckets / bucket_place / bucket_csr: CSR build
//  2. y1 = (X @ W1) * dinv[row]            (MFMA bf16, fp32 X staged->bf16)
//  3. h1[d] = relu(dinv[d]*(y1[d]+sum)+b1) (wave/node gather, bf16 in/out)
//  4. y2 = (h1 @ W2) * dinv[row]           (MFMA bf16)
//  5. h2[d] = dinv[d]*(y2[d]+sum)+b2       (bf16)
//  6. score[e] = dot64(h2[src], h2[dst])   (fp32 out)

#define DIN 128
#define DH  128
#define DOUT 64
#define CAP 8192   // max edges per 256-node bucket (mean ~4096)

typedef __attribute__((ext_vector_type(8))) short short8;
typedef __attribute__((ext_vector_type(4))) float floatx4;

__device__ inline float2 bf2_to_f2(unsigned u) {
    union { unsigned i; float f; } a, b;
    a.i = u << 16;          // low bf16
    b.i = u & 0xffff0000u;  // high bf16
    return make_float2(a.f, b.f);
}
__device__ inline float bf_to_f(unsigned short u) {
    union { unsigned i; float f; } a;
    a.i = ((unsigned)u) << 16;
    return a.f;
}
__device__ inline unsigned short f_to_bf(float f) {  // RNE
    union { float f; unsigned i; } v; v.f = f;
    unsigned r = v.i + 0x7fffu + ((v.i >> 16) & 1u);
    return (unsigned short)(r >> 16);
}

__global__ __launch_bounds__(256) void bucket_count_kernel(const int* __restrict__ dst,
                                                           int* __restrict__ gcnt,
                                                           int E, int nbuck) {
    __shared__ int hist[256];
    int t = threadIdx.x;
    hist[t] = 0;
    __syncthreads();
    int base = blockIdx.x * 4096 + t;
#pragma unroll
    for (int it = 0; it < 16; ++it) {
        int e = base + it * 256;
        if (e < E) atomicAdd(&hist[dst[e] >> 8], 1);
    }
    __syncthreads();
    if (t < nbuck && hist[t]) atomicAdd(&gcnt[t], hist[t]);
}

__global__ __launch_bounds__(256) void scan_buckets_kernel(const int* __restrict__ gcnt,
                                                           int* __restrict__ gbase,
                                                           int* __restrict__ gcursor,
                                                           int* __restrict__ row_ptr,
                                                           int nbuck, int N, int E) {
    __shared__ int lds[256];
    int t = threadIdx.x;
    int v = (t < nbuck) ? gcnt[t] : 0;
    lds[t] = v;
    __syncthreads();
    for (int off = 1; off < 256; off <<= 1) {
        int u = (t >= off) ? lds[t - off] : 0;
        __syncthreads();
        lds[t] += u;
        __syncthreads();
    }
    int ex = lds[t] - v;
    if (t < nbuck) { gbase[t] = ex; gcursor[t] = ex; }
    if (t == 0) { gbase[nbuck] = E; row_ptr[N] = E; }
}

__global__ __launch_bounds__(256) void bucket_place_kernel(const int* __restrict__ src,
                                                           const int* __restrict__ dst,
                                                           int* __restrict__ gcursor,
                                                           uint2* __restrict__ tmp,
                                                           int E, int nbuck) {
    __shared__ int hist[256];
    __shared__ int cur[256];
    int t = threadIdx.x;
    hist[t] = 0;
    __syncthreads();
    int base = blockIdx.x * 4096 + t;
    int d[16];
#pragma unroll
    for (int it = 0; it < 16; ++it) {
        int e = base + it * 256;
        d[it] = (e < E) ? dst[e] : -1;
        if (d[it] >= 0) atomicAdd(&hist[d[it] >> 8], 1);
    }
    __syncthreads();
    if (t < nbuck && hist[t]) cur[t] = atomicAdd(&gcursor[t], hist[t]);
    __syncthreads();
#pragma unroll
    for (int it = 0; it < 16; ++it) {
        int e = base + it * 256;
        if (d[it] >= 0) {
            int r = atomicAdd(&cur[d[it] >> 8], 1);
            tmp[r] = make_uint2((unsigned)src[e], (unsigned)d[it]);
        }
    }
}

// One block per bucket: LDS counting sort by dst&255 -> col (coalesced),
// row_ptr, dinv.
__global__ __launch_bounds__(256) void bucket_csr_kernel(const uint2* __restrict__ tmp,
                                                         const int* __restrict__ gbase,
                                                         int* __restrict__ row_ptr,
                                                         float* __restrict__ dinv,
                                                         int* __restrict__ col, int N) {
    __shared__ int hist[256], cur[256], pfx[256];
    __shared__ unsigned esrc[CAP];
    __shared__ unsigned char eloc[CAP];
    __shared__ unsigned sorted[CAP];
    int b = blockIdx.x, t = threadIdx.x;
    int beg = gbase[b], end = gbase[b + 1];
    int size = end - beg;
    if (size > CAP) size = CAP;  // statistically unreachable; memory-safety
    hist[t] = 0;
    __syncthreads();
    for (int i = t; i < size; i += 256) {
        uint2 e = tmp[beg + i];
        esrc[i] = e.x;
        int loc = e.y & 255;
        eloc[i] = (unsigned char)loc;
        atomicAdd(&hist[loc], 1);
    }
    __syncthreads();
    int v = hist[t];
    pfx[t] = v;
    __syncthreads();
    for (int off = 1; off < 256; off <<= 1) {
        int u = (t >= off) ? pfx[t - off] : 0;
        __syncthreads();
        pfx[t] += u;
        __syncthreads();
    }
    int ex = pfx[t] - v;
    cur[t] = ex;
    int node = b * 256 + t;
    if (node < N) {
        row_ptr[node] = beg + ex;
        dinv[node] = rsqrtf((float)(v + 1));
    }
    __syncthreads();
    for (int i = t; i < size; i += 256) {
        int r = atomicAdd(&cur[eloc[i]], 1);
        sorted[r] = esrc[i];
    }
    __syncthreads();
    for (int i = t; i < size; i += 256) col[beg + i] = (int)sorted[i];
}

// MFMA bf16 GEMM: Y[r][c] = bf16( dinv[r] * sum_k X[r][k]*W[k][c] ).
// Block: 128 rows x COLS, 256 threads = 4 waves.
// Wave wv owns rows [wv*32, wv*32+32) x ALL COLS (4 waves x 32 = 128 rows).
// Full K=128 staged in LDS as bf16, row pad 136 (16B-aligned; 2-way bank
// aliasing max = free). v_mfma_f32_16x16x32_bf16:
//   A/B frag: [m|n = lane&15][k = (lane>>4)*8 + j]  (short8, b128 read)
//   C/D:      col = lane&15, row = (lane>>4)*4 + reg
template <int COLS, typename XT>
__global__ __launch_bounds__(256) void mfma_gemm_kernel(const XT* __restrict__ X,
                                                        const float* __restrict__ W,
                                                        const float* __restrict__ dinv,
                                                        unsigned short* __restrict__ Y,
                                                        int nrows) {
    constexpr int KP = 136;                       // padded K stride (shorts)
    __shared__ unsigned short Xs[128 * KP];
    __shared__ unsigned short Wt[COLS * KP];      // [n][k] transposed
    int tid = threadIdx.x;
    int row0 = blockIdx.x * 128;

    // ---- stage X (rows) ----
    if constexpr (std::is_same_v<XT, float>) {
#pragma unroll
        for (int it = 0; it < 16; ++it) {
            int idx = it * 256 + tid;             // [0, 4096): float4 units
            int r = idx >> 5;                     // 0..127
            int c4 = (idx & 31) * 4;              // k, multiple of 4
            int gr = row0 + r; if (gr >= nrows) gr = nrows - 1;
            float4 v = *(const float4*)(X + (size_t)gr * 128 + c4);
            ushort4 p;
            p.x = f_to_bf(v.x); p.y = f_to_bf(v.y);
            p.z = f_to_bf(v.z); p.w = f_to_bf(v.w);
            *(ushort4*)&Xs[r * KP + c4] = p;
        }
    } else {
#pragma unroll
        for (int it = 0; it < 8; ++it) {
            int idx = it * 256 + tid;             // [0, 2048): 8-bf16 units
            int r = idx >> 4;
            int c8 = (idx & 15) * 8;
            int gr = row0 + r; if (gr >= nrows) gr = nrows - 1;
            uint4 v = *(const uint4*)(X + (size_t)gr * 128 + c8);
            *(uint4*)&Xs[r * KP + c8] = v;
        }
    }
    // ---- stage W transposed: Wt[n][k] <- W[k][n] ----
#pragma unroll
    for (int it = 0; it < COLS / 8; ++it) {       // COLS*32 quads / 256
        int idx = it * 256 + tid;
        int n = idx >> 5;                         // 0..COLS-1
        int k4 = (idx & 31) * 4;
        ushort4 p;
        p.x = f_to_bf(W[(size_t)(k4 + 0) * COLS + n]);
        p.y = f_to_bf(W[(size_t)(k4 + 1) * COLS + n]);
        p.z = f_to_bf(W[(size_t)(k4 + 2) * COLS + n]);
        p.w = f_to_bf(W[(size_t)(k4 + 3) * COLS + n]);
        *(ushort4*)&Wt[n * KP + k4] = p;
    }
    __syncthreads();

    // ---- MFMA compute: wave wv -> rows [wv*32, wv*32+32), all COLS ----
    constexpr int CT = COLS / 16;                 // col tiles per wave (8 or 4)
    int wv = tid >> 6, lane = tid & 63;
    int lr = lane & 15;
    int lk = (lane >> 4) * 8;
    int rw = wv * 32;                             // wave row base (2 tiles)

    floatx4 acc[2][CT];
#pragma unroll
    for (int rt = 0; rt < 2; ++rt)
#pragma unroll
        for (int ct = 0; ct < CT; ++ct) acc[rt][ct] = (floatx4){0.f, 0.f, 0.f, 0.f};

#pragma unroll
    for (int kk = 0; kk < 128; kk += 32) {
        short8 a[2], b[CT];
#pragma unroll
        for (int rt = 0; rt < 2; ++rt)
            a[rt] = *(const short8*)&Xs[(rw + rt * 16 + lr) * KP + kk + lk];
#pragma unroll
        for (int ct = 0; ct < CT; ++ct)
            b[ct] = *(const short8*)&Wt[(ct * 16 + lr) * KP + kk + lk];
#pragma unroll
        for (int rt = 0; rt < 2; ++rt)
#pragma unroll
            for (int ct = 0; ct < CT; ++ct)
                acc[rt][ct] = __builtin_amdgcn_mfma_f32_16x16x32_bf16(
                    a[rt], b[ct], acc[rt][ct], 0, 0, 0);
    }

    // ---- epilogue: scale by dinv[row], bf16 store ----
#pragma unroll
    for (int rt = 0; rt < 2; ++rt) {
#pragma unroll
        for (int i = 0; i < 4; ++i) {
            int grow = row0 + rw + rt * 16 + (lane >> 4) * 4 + i;
            if (grow >= nrows) continue;
            float dv = dinv[grow];
#pragma unroll
            for (int ct = 0; ct < CT; ++ct)
                Y[(size_t)grow * COLS + ct * 16 + lr] =
                    f_to_bf(acc[rt][ct][i] * dv);
        }
    }
}

// One wave per node: out[d] = act(dinv[d]*(y[d] + sum_{s in CSR[d]} y[s]) + b)
// y and out are bf16 tables; accumulate fp32. Edge loop unrolled x8 for MLP.
template <int D, bool RELU>
__global__ __launch_bounds__(256) void agg_kernel(const unsigned short* __restrict__ y,
                                                  const int* __restrict__ row_ptr,
                                                  const int* __restrict__ col,
                                                  const float* __restrict__ dinv,
                                                  const float* __restrict__ bias,
                                                  unsigned short* __restrict__ out, int n) {
    constexpr int V = D / 64;  // bf16 per lane (2 for D=128, 1 for D=64)
    int w = (blockIdx.x * 256 + threadIdx.x) >> 6;
    int lane = threadIdx.x & 63;
    if (w >= n) return;
    float acc[V];
    if constexpr (V == 2) {
        float2 t = bf2_to_f2(*(const unsigned*)(y + (size_t)w * D + lane * 2));
        acc[0] = t.x; acc[1] = t.y;
    } else {
        acc[0] = bf_to_f(y[(size_t)w * D + lane]);
    }
    int beg = row_ptr[w], end = row_ptr[w + 1];
    int i = beg;
    for (; i + 8 <= end; i += 8) {
        int s[8];
#pragma unroll
        for (int u = 0; u < 8; ++u) s[u] = col[i + u];
        if constexpr (V == 2) {
            unsigned tv[8];
#pragma unroll
            for (int u = 0; u < 8; ++u)
                tv[u] = *(const unsigned*)(y + (size_t)s[u] * D + lane * 2);
#pragma unroll
            for (int u = 0; u < 8; ++u) {
                float2 f = bf2_to_f2(tv[u]);
                acc[0] += f.x; acc[1] += f.y;
            }
        } else {
            unsigned short tv[8];
#pragma unroll
            for (int u = 0; u < 8; ++u) tv[u] = y[(size_t)s[u] * D + lane];
#pragma unroll
            for (int u = 0; u < 8; ++u) acc[0] += bf_to_f(tv[u]);
        }
    }
    for (; i < end; ++i) {
        int s = col[i];
        if constexpr (V == 2) {
            float2 f = bf2_to_f2(*(const unsigned*)(y + (size_t)s * D + lane * 2));
            acc[0] += f.x; acc[1] += f.y;
        } else {
            acc[0] += bf_to_f(y[(size_t)s * D + lane]);
        }
    }
    float dv = dinv[w];
    if constexpr (V == 2) {
        float r0 = fmaf(dv, acc[0], bias[lane * 2]);
        float r1 = fmaf(dv, acc[1], bias[lane * 2 + 1]);
        if (RELU) { r0 = fmaxf(r0, 0.f); r1 = fmaxf(r1, 0.f); }
        unsigned pk = (unsigned)f_to_bf(r0) | ((unsigned)f_to_bf(r1) << 16);
        *(unsigned*)(out + (size_t)w * D + lane * 2) = pk;
    } else {
        float r = fmaf(dv, acc[0], bias[lane]);
        if (RELU) r = fmaxf(r, 0.f);
        out[(size_t)w * D + lane] = f_to_bf(r);
    }
}

// 16 lanes per edge, 4 bf16 (8B) per lane over D=64.
__global__ __launch_bounds__(256) void score_kernel(const unsigned short* __restrict__ h2,
                                                    const int* __restrict__ src,
                                                    const int* __restrict__ dst,
                                                    float* __restrict__ out, int E) {
    int tid = blockIdx.x * 256 + threadIdx.x;
    int e = tid >> 4;
    if (e >= E) return;
    int q = tid & 15;
    int s = src[e], d = dst[e];
    uint2 ua = *(const uint2*)(h2 + (size_t)s * 64 + q * 4);
    uint2 ub = *(const uint2*)(h2 + (size_t)d * 64 + q * 4);
    float2 a0 = bf2_to_f2(ua.x), a1 = bf2_to_f2(ua.y);
    float2 b0 = bf2_to_f2(ub.x), b1 = bf2_to_f2(ub.y);
    float v = a0.x * b0.x + a0.y * b0.y + a1.x * b1.x + a1.y * b1.y;
    v += __shfl_xor(v, 8);
    v += __shfl_xor(v, 4);
    v += __shfl_xor(v, 2);
    v += __shfl_xor(v, 1);
    if (q == 0) out[e] = v;
}

extern "C" void kernel_launch(void* const* d_in, const int* in_sizes, int n_in,
                              void* d_out, int out_size, void* d_ws, size_t ws_size,
                              hipStream_t stream) {
    const float* X   = (const float*)d_in[0];
    const int*   src = (const int*)d_in[1];
    const int*   dst = (const int*)d_in[2];
    const float* W1  = (const float*)d_in[3];
    const float* b1  = (const float*)d_in[4];
    const float* W2  = (const float*)d_in[5];
    const float* b2  = (const float*)d_in[6];
    float* score = (float*)d_out;

    const int N = in_sizes[0] / DIN;     // 50000
    const int E = in_sizes[1];           // 800000
    const int nbuck = (N + 255) / 256;   // 196 buckets
    const int EB = (E + 4095) / 4096;    // edge blocks for bucket passes

    // workspace carve-up (256B aligned)
    auto align = [](size_t x) { return (x + 255) & ~(size_t)255; };
    char* p = (char*)d_ws;
    int*   gcnt    = (int*)p;               p += align(256 * 4);
    int*   gbase   = (int*)p;               p += align(257 * 4);
    int*   gcursor = (int*)p;               p += align(256 * 4);
    int*   row_ptr = (int*)p;               p += align((size_t)(N + 1) * 4);
    float* dinv    = (float*)p;             p += align((size_t)N * 4);
    int*   col     = (int*)p;               p += align((size_t)E * 4);
    uint2* tmp     = (uint2*)p;             p += align((size_t)E * 8);
    unsigned short* y1 = (unsigned short*)p; p += align((size_t)N * DH * 2);
    unsigned short* h1 = (unsigned short*)p; p += align((size_t)N * DH * 2);
    unsigned short* y2 = y1;                       // y1 dead after h1
    unsigned short* h2 = y1 + (size_t)N * DOUT;    // second half of y1 region

    hipMemsetAsync(gcnt, 0, 256 * 4, stream);

    bucket_count_kernel<<<EB, 256, 0, stream>>>(dst, gcnt, E, nbuck);
    scan_buckets_kernel<<<1, 256, 0, stream>>>(gcnt, gbase, gcursor, row_ptr, nbuck, N, E);
    bucket_place_kernel<<<EB, 256, 0, stream>>>(src, dst, gcursor, tmp, E, nbuck);
    bucket_csr_kernel<<<nbuck, 256, 0, stream>>>(tmp, gbase, row_ptr, dinv, col, N);

    int gemm_blocks = (N + 127) / 128;
    mfma_gemm_kernel<DH, float><<<gemm_blocks, 256, 0, stream>>>(X, W1, dinv, y1, N);

    int agg_blocks = (N + 3) / 4;
    agg_kernel<DH, true><<<agg_blocks, 256, 0, stream>>>(y1, row_ptr, col, dinv, b1, h1, N);

    mfma_gemm_kernel<DOUT, unsigned short><<<gemm_blocks, 256, 0, stream>>>(h1, W2, dinv, y2, N);
    agg_kernel<DOUT, false><<<agg_blocks, 256, 0, stream>>>(y2, row_ptr, col, dinv, b2, h2, N);

    int score_blocks = (E * 16 + 255) / 256;
    score_kernel<<<score_blocks, 256, 0, stream>>>(h2, src, dst, score, E);
}

// Round 8
// 255.891 us; speedup vs baseline: 2.2546x; 1.0205x over previous
//
#include <hip/hip_runtime.h>
#include <hip/hip_bf16.h>
#include <type_traits>

// GCN 2-layer + edge predictor. bf16 tables, MFMA GEMMs, counting-sort CSR.
// Score is node-centric over the CSR (dst row register-resident; only the
// src row is a random gather), scattering to score[eidx] via the edge-id
// permutation carried through the counting sort.
//
// Pipeline per call:
//  1. bucket_count / scan_buckets / bucket_place / bucket_csr: CSR build
//     (col[] = srcs sorted by dst, eidx[] = original edge id per CSR slot)
//  2. y1 = (X @ W1) * dinv[row]            (MFMA bf16)
//  3. h1[d] = relu(dinv[d]*(y1[d]+sum)+b1) (wave/node gather)
//  4. y2 = (h1 @ W2) * dinv[row]           (MFMA bf16)
//  5. h2[d] = dinv[d]*(y2[d]+sum)+b2
//  6. score[eidx] = dot64(h2[dst], h2[src]) (wave/node over CSR run)

#define DIN 128
#define DH  128
#define DOUT 64
#define CAP 8192   // max edges per 256-node bucket (mean ~4096)

typedef __attribute__((ext_vector_type(8))) short short8;
typedef __attribute__((ext_vector_type(4))) float floatx4;

__device__ inline float2 bf2_to_f2(unsigned u) {
    union { unsigned i; float f; } a, b;
    a.i = u << 16;          // low bf16
    b.i = u & 0xffff0000u;  // high bf16
    return make_float2(a.f, b.f);
}
__device__ inline float bf_to_f(unsigned short u) {
    union { unsigned i; float f; } a;
    a.i = ((unsigned)u) << 16;
    return a.f;
}
__device__ inline unsigned short f_to_bf(float f) {  // RNE
    union { float f; unsigned i; } v; v.f = f;
    unsigned r = v.i + 0x7fffu + ((v.i >> 16) & 1u);
    return (unsigned short)(r >> 16);
}

__global__ __launch_bounds__(256) void bucket_count_kernel(const int* __restrict__ dst,
                                                           int* __restrict__ gcnt,
                                                           int E, int nbuck) {
    __shared__ int hist[256];
    int t = threadIdx.x;
    hist[t] = 0;
    __syncthreads();
    int base = blockIdx.x * 4096 + t;
#pragma unroll
    for (int it = 0; it < 16; ++it) {
        int e = base + it * 256;
        if (e < E) atomicAdd(&hist[dst[e] >> 8], 1);
    }
    __syncthreads();
    if (t < nbuck && hist[t]) atomicAdd(&gcnt[t], hist[t]);
}

__global__ __launch_bounds__(256) void scan_buckets_kernel(const int* __restrict__ gcnt,
                                                           int* __restrict__ gbase,
                                                           int* __restrict__ gcursor,
                                                           int* __restrict__ row_ptr,
                                                           int nbuck, int N, int E) {
    __shared__ int lds[256];
    int t = threadIdx.x;
    int v = (t < nbuck) ? gcnt[t] : 0;
    lds[t] = v;
    __syncthreads();
    for (int off = 1; off < 256; off <<= 1) {
        int u = (t >= off) ? lds[t - off] : 0;
        __syncthreads();
        lds[t] += u;
        __syncthreads();
    }
    int ex = lds[t] - v;
    if (t < nbuck) { gbase[t] = ex; gcursor[t] = ex; }
    if (t == 0) { gbase[nbuck] = E; row_ptr[N] = E; }
}

// tmp.x = src | (dst&255)<<16  (src < 65536), tmp.y = original edge index.
__global__ __launch_bounds__(256) void bucket_place_kernel(const int* __restrict__ src,
                                                           const int* __restrict__ dst,
                                                           int* __restrict__ gcursor,
                                                           uint2* __restrict__ tmp,
                                                           int E, int nbuck) {
    __shared__ int hist[256];
    __shared__ int cur[256];
    int t = threadIdx.x;
    hist[t] = 0;
    __syncthreads();
    int base = blockIdx.x * 4096 + t;
    int d[16];
#pragma unroll
    for (int it = 0; it < 16; ++it) {
        int e = base + it * 256;
        d[it] = (e < E) ? dst[e] : -1;
        if (d[it] >= 0) atomicAdd(&hist[d[it] >> 8], 1);
    }
    __syncthreads();
    if (t < nbuck && hist[t]) cur[t] = atomicAdd(&gcursor[t], hist[t]);
    __syncthreads();
#pragma unroll
    for (int it = 0; it < 16; ++it) {
        int e = base + it * 256;
        if (d[it] >= 0) {
            int r = atomicAdd(&cur[d[it] >> 8], 1);
            tmp[r] = make_uint2((unsigned)src[e] | ((unsigned)(d[it] & 255) << 16),
                                (unsigned)e);
        }
    }
}

// One block per bucket: LDS counting sort by dst&255 ->
// col[] (srcs, coalesced), eidx[] (edge ids), row_ptr, dinv.
__global__ __launch_bounds__(256) void bucket_csr_kernel(const uint2* __restrict__ tmp,
                                                         const int* __restrict__ gbase,
                                                         int* __restrict__ row_ptr,
                                                         float* __restrict__ dinv,
                                                         int* __restrict__ col,
                                                         int* __restrict__ eidx, int N) {
    __shared__ int hist[256], cur[256], pfx[256];
    __shared__ unsigned ebuf[CAP];     // src | loc<<16
    __shared__ unsigned ibuf[CAP];     // edge id
    __shared__ unsigned ssrc[CAP];
    __shared__ unsigned sidx[CAP];
    int b = blockIdx.x, t = threadIdx.x;
    int beg = gbase[b], end = gbase[b + 1];
    int size = end - beg;
    if (size > CAP) size = CAP;  // statistically unreachable; memory-safety
    hist[t] = 0;
    __syncthreads();
    for (int i = t; i < size; i += 256) {
        uint2 e = tmp[beg + i];
        ebuf[i] = e.x;
        ibuf[i] = e.y;
        atomicAdd(&hist[e.x >> 16], 1);
    }
    __syncthreads();
    int v = hist[t];
    pfx[t] = v;
    __syncthreads();
    for (int off = 1; off < 256; off <<= 1) {
        int u = (t >= off) ? pfx[t - off] : 0;
        __syncthreads();
        pfx[t] += u;
        __syncthreads();
    }
    int ex = pfx[t] - v;
    cur[t] = ex;
    int node = b * 256 + t;
    if (node < N) {
        row_ptr[node] = beg + ex;
        dinv[node] = rsqrtf((float)(v + 1));
    }
    __syncthreads();
    for (int i = t; i < size; i += 256) {
        int r = atomicAdd(&cur[ebuf[i] >> 16], 1);
        ssrc[r] = ebuf[i] & 0xffffu;
        sidx[r] = ibuf[i];
    }
    __syncthreads();
    for (int i = t; i < size; i += 256) {
        col[beg + i]  = (int)ssrc[i];
        eidx[beg + i] = (int)sidx[i];
    }
}

// MFMA bf16 GEMM: Y[r][c] = bf16( dinv[r] * sum_k X[r][k]*W[k][c] ).
// Block: 128 rows x COLS, 256 threads = 4 waves; wave wv owns rows
// [wv*32, wv*32+32) x ALL COLS. Full K=128 in LDS, row pad 136.
template <int COLS, typename XT>
__global__ __launch_bounds__(256) void mfma_gemm_kernel(const XT* __restrict__ X,
                                                        const float* __restrict__ W,
                                                        const float* __restrict__ dinv,
                                                        unsigned short* __restrict__ Y,
                                                        int nrows) {
    constexpr int KP = 136;                       // padded K stride (shorts)
    __shared__ unsigned short Xs[128 * KP];
    __shared__ unsigned short Wt[COLS * KP];      // [n][k] transposed
    int tid = threadIdx.x;
    int row0 = blockIdx.x * 128;

    // ---- stage X (rows) ----
    if constexpr (std::is_same_v<XT, float>) {
#pragma unroll
        for (int it = 0; it < 16; ++it) {
            int idx = it * 256 + tid;             // [0, 4096): float4 units
            int r = idx >> 5;                     // 0..127
            int c4 = (idx & 31) * 4;              // k, multiple of 4
            int gr = row0 + r; if (gr >= nrows) gr = nrows - 1;
            float4 v = *(const float4*)(X + (size_t)gr * 128 + c4);
            ushort4 p;
            p.x = f_to_bf(v.x); p.y = f_to_bf(v.y);
            p.z = f_to_bf(v.z); p.w = f_to_bf(v.w);
            *(ushort4*)&Xs[r * KP + c4] = p;
        }
    } else {
#pragma unroll
        for (int it = 0; it < 8; ++it) {
            int idx = it * 256 + tid;             // [0, 2048): 8-bf16 units
            int r = idx >> 4;
            int c8 = (idx & 15) * 8;
            int gr = row0 + r; if (gr >= nrows) gr = nrows - 1;
            uint4 v = *(const uint4*)(X + (size_t)gr * 128 + c8);
            *(uint4*)&Xs[r * KP + c8] = v;
        }
    }
    // ---- stage W transposed: Wt[n][k] <- W[k][n] ----
#pragma unroll
    for (int it = 0; it < COLS / 8; ++it) {       // COLS*32 quads / 256
        int idx = it * 256 + tid;
        int n = idx >> 5;                         // 0..COLS-1
        int k4 = (idx & 31) * 4;
        ushort4 p;
        p.x = f_to_bf(W[(size_t)(k4 + 0) * COLS + n]);
        p.y = f_to_bf(W[(size_t)(k4 + 1) * COLS + n]);
        p.z = f_to_bf(W[(size_t)(k4 + 2) * COLS + n]);
        p.w = f_to_bf(W[(size_t)(k4 + 3) * COLS + n]);
        *(ushort4*)&Wt[n * KP + k4] = p;
    }
    __syncthreads();

    // ---- MFMA compute: wave wv -> rows [wv*32, wv*32+32), all COLS ----
    constexpr int CT = COLS / 16;                 // col tiles per wave (8 or 4)
    int wv = tid >> 6, lane = tid & 63;
    int lr = lane & 15;
    int lk = (lane >> 4) * 8;
    int rw = wv * 32;                             // wave row base (2 tiles)

    floatx4 acc[2][CT];
#pragma unroll
    for (int rt = 0; rt < 2; ++rt)
#pragma unroll
        for (int ct = 0; ct < CT; ++ct) acc[rt][ct] = (floatx4){0.f, 0.f, 0.f, 0.f};

#pragma unroll
    for (int kk = 0; kk < 128; kk += 32) {
        short8 a[2], b[CT];
#pragma unroll
        for (int rt = 0; rt < 2; ++rt)
            a[rt] = *(const short8*)&Xs[(rw + rt * 16 + lr) * KP + kk + lk];
#pragma unroll
        for (int ct = 0; ct < CT; ++ct)
            b[ct] = *(const short8*)&Wt[(ct * 16 + lr) * KP + kk + lk];
#pragma unroll
        for (int rt = 0; rt < 2; ++rt)
#pragma unroll
            for (int ct = 0; ct < CT; ++ct)
                acc[rt][ct] = __builtin_amdgcn_mfma_f32_16x16x32_bf16(
                    a[rt], b[ct], acc[rt][ct], 0, 0, 0);
    }

    // ---- epilogue: scale by dinv[row], bf16 store ----
#pragma unroll
    for (int rt = 0; rt < 2; ++rt) {
#pragma unroll
        for (int i = 0; i < 4; ++i) {
            int grow = row0 + rw + rt * 16 + (lane >> 4) * 4 + i;
            if (grow >= nrows) continue;
            float dv = dinv[grow];
#pragma unroll
            for (int ct = 0; ct < CT; ++ct)
                Y[(size_t)grow * COLS + ct * 16 + lr] =
                    f_to_bf(acc[rt][ct][i] * dv);
        }
    }
}

// One wave per node: out[d] = act(dinv[d]*(y[d] + sum_{s in CSR[d]} y[s]) + b)
// y and out are bf16 tables; accumulate fp32. Edge loop unrolled x8 for MLP.
template <int D, bool RELU>
__global__ __launch_bounds__(256) void agg_kernel(const unsigned short* __restrict__ y,
                                                  const int* __restrict__ row_ptr,
                                                  const int* __restrict__ col,
                                                  const float* __restrict__ dinv,
                                                  const float* __restrict__ bias,
                                                  unsigned short* __restrict__ out, int n) {
    constexpr int V = D / 64;  // bf16 per lane (2 for D=128, 1 for D=64)
    int w = (blockIdx.x * 256 + threadIdx.x) >> 6;
    int lane = threadIdx.x & 63;
    if (w >= n) return;
    float acc[V];
    if constexpr (V == 2) {
        float2 t = bf2_to_f2(*(const unsigned*)(y + (size_t)w * D + lane * 2));
        acc[0] = t.x; acc[1] = t.y;
    } else {
        acc[0] = bf_to_f(y[(size_t)w * D + lane]);
    }
    int beg = row_ptr[w], end = row_ptr[w + 1];
    int i = beg;
    for (; i + 8 <= end; i += 8) {
        int s[8];
#pragma unroll
        for (int u = 0; u < 8; ++u) s[u] = col[i + u];
        if constexpr (V == 2) {
            unsigned tv[8];
#pragma unroll
            for (int u = 0; u < 8; ++u)
                tv[u] = *(const unsigned*)(y + (size_t)s[u] * D + lane * 2);
#pragma unroll
            for (int u = 0; u < 8; ++u) {
                float2 f = bf2_to_f2(tv[u]);
                acc[0] += f.x; acc[1] += f.y;
            }
        } else {
            unsigned short tv[8];
#pragma unroll
            for (int u = 0; u < 8; ++u) tv[u] = y[(size_t)s[u] * D + lane];
#pragma unroll
            for (int u = 0; u < 8; ++u) acc[0] += bf_to_f(tv[u]);
        }
    }
    for (; i < end; ++i) {
        int s = col[i];
        if constexpr (V == 2) {
            float2 f = bf2_to_f2(*(const unsigned*)(y + (size_t)s * D + lane * 2));
            acc[0] += f.x; acc[1] += f.y;
        } else {
            acc[0] += bf_to_f(y[(size_t)s * D + lane]);
        }
    }
    float dv = dinv[w];
    if constexpr (V == 2) {
        float r0 = fmaf(dv, acc[0], bias[lane * 2]);
        float r1 = fmaf(dv, acc[1], bias[lane * 2 + 1]);
        if (RELU) { r0 = fmaxf(r0, 0.f); r1 = fmaxf(r1, 0.f); }
        unsigned pk = (unsigned)f_to_bf(r0) | ((unsigned)f_to_bf(r1) << 16);
        *(unsigned*)(out + (size_t)w * D + lane * 2) = pk;
    } else {
        float r = fmaf(dv, acc[0], bias[lane]);
        if (RELU) r = fmaxf(r, 0.f);
        out[(size_t)w * D + lane] = f_to_bf(r);
    }
}

// Node-centric score: one wave per dst node. h2[dst] held in registers
// (each lane: 8 bf16 for its group-local slot), 8 groups x 8 lanes process
// 8 edges/iter; each group reads one random h2[src] row (128 B coalesced),
// dots, reduces over 8 lanes, scatters to score[eidx].
__global__ __launch_bounds__(256) void score_csr_kernel(const unsigned short* __restrict__ h2,
                                                        const int* __restrict__ row_ptr,
                                                        const int* __restrict__ col,
                                                        const int* __restrict__ eidx,
                                                        float* __restrict__ out, int n) {
    int w = (blockIdx.x * 256 + threadIdx.x) >> 6;
    int lane = threadIdx.x & 63;
    if (w >= n) return;
    int q = lane & 7;                 // position within group (8 x 8 bf16 = 64)
    // dst row fragment: 8 bf16 at [q*8, q*8+8)
    uint4 hd = *(const uint4*)(h2 + (size_t)w * 64 + q * 8);
    float d0[8];
    { float2 f;
      f = bf2_to_f2(hd.x); d0[0] = f.x; d0[1] = f.y;
      f = bf2_to_f2(hd.y); d0[2] = f.x; d0[3] = f.y;
      f = bf2_to_f2(hd.z); d0[4] = f.x; d0[5] = f.y;
      f = bf2_to_f2(hd.w); d0[6] = f.x; d0[7] = f.y; }
    int beg = row_ptr[w], end = row_ptr[w + 1];
    int g = lane >> 3;                // edge group 0..7
    for (int i = beg; i < end; i += 8) {
        int ei = i + g;
        bool ok = ei < end;
        int s = ok ? col[ei] : 0;
        uint4 hs = *(const uint4*)(h2 + (size_t)s * 64 + q * 8);
        float v = 0.f;
        float2 f;
        f = bf2_to_f2(hs.x); v = fmaf(d0[0], f.x, v); v = fmaf(d0[1], f.y, v);
        f = bf2_to_f2(hs.y); v = fmaf(d0[2], f.x, v); v = fmaf(d0[3], f.y, v);
        f = bf2_to_f2(hs.z); v = fmaf(d0[4], f.x, v); v = fmaf(d0[5], f.y, v);
        f = bf2_to_f2(hs.w); v = fmaf(d0[6], f.x, v); v = fmaf(d0[7], f.y, v);
        v += __shfl_xor(v, 4);
        v += __shfl_xor(v, 2);
        v += __shfl_xor(v, 1);
        if (ok && q == 0) out[eidx[ei]] = v;
    }
}

extern "C" void kernel_launch(void* const* d_in, const int* in_sizes, int n_in,
                              void* d_out, int out_size, void* d_ws, size_t ws_size,
                              hipStream_t stream) {
    const float* X   = (const float*)d_in[0];
    const int*   src = (const int*)d_in[1];
    const int*   dst = (const int*)d_in[2];
    const float* W1  = (const float*)d_in[3];
    const float* b1  = (const float*)d_in[4];
    const float* W2  = (const float*)d_in[5];
    const float* b2  = (const float*)d_in[6];
    float* score = (float*)d_out;

    const int N = in_sizes[0] / DIN;     // 50000
    const int E = in_sizes[1];           // 800000
    const int nbuck = (N + 255) / 256;   // 196 buckets
    const int EB = (E + 4095) / 4096;    // edge blocks for bucket passes

    // workspace carve-up (256B aligned)
    auto align = [](size_t x) { return (x + 255) & ~(size_t)255; };
    char* p = (char*)d_ws;
    int*   gcnt    = (int*)p;               p += align(256 * 4);
    int*   gbase   = (int*)p;               p += align(257 * 4);
    int*   gcursor = (int*)p;               p += align(256 * 4);
    int*   row_ptr = (int*)p;               p += align((size_t)(N + 1) * 4);
    float* dinv    = (float*)p;             p += align((size_t)N * 4);
    int*   col     = (int*)p;               p += align((size_t)E * 4);
    int*   eidx    = (int*)p;               p += align((size_t)E * 4);
    uint2* tmp     = (uint2*)p;             p += align((size_t)E * 8);
    unsigned short* y1 = (unsigned short*)p; p += align((size_t)N * DH * 2);
    unsigned short* h1 = (unsigned short*)p; p += align((size_t)N * DH * 2);
    unsigned short* y2 = y1;                       // y1 dead after h1
    unsigned short* h2 = y1 + (size_t)N * DOUT;    // second half of y1 region

    hipMemsetAsync(gcnt, 0, 256 * 4, stream);

    bucket_count_kernel<<<EB, 256, 0, stream>>>(dst, gcnt, E, nbuck);
    scan_buckets_kernel<<<1, 256, 0, stream>>>(gcnt, gbase, gcursor, row_ptr, nbuck, N, E);
    bucket_place_kernel<<<EB, 256, 0, stream>>>(src, dst, gcursor, tmp, E, nbuck);
    bucket_csr_kernel<<<nbuck, 256, 0, stream>>>(tmp, gbase, row_ptr, dinv, col, eidx, N);

    int gemm_blocks = (N + 127) / 128;
    mfma_gemm_kernel<DH, float><<<gemm_blocks, 256, 0, stream>>>(X, W1, dinv, y1, N);

    int agg_blocks = (N + 3) / 4;
    agg_kernel<DH, true><<<agg_blocks, 256, 0, stream>>>(y1, row_ptr, col, dinv, b1, h1, N);

    mfma_gemm_kernel<DOUT, unsigned short><<<gemm_blocks, 256, 0, stream>>>(h1, W2, dinv, y2, N);
    agg_kernel<DOUT, false><<<agg_blocks, 256, 0, stream>>>(y2, row_ptr, col, dinv, b2, h2, N);

    score_csr_kernel<<<agg_blocks, 256, 0, stream>>>(h2, row_ptr, col, eidx, score, N);
}